// Round 1
// baseline (4167.117 us; speedup 1.0000x reference)
//
#include <hip/hip_runtime.h>
#include <math.h>

#define B_SZ 512
#define SEQ 3
#define D_MODEL 1550
#define ED 3100
#define NSTATE 16
#define DTR 97
#define DBC_R 129   // DTR + 2*NSTATE
#define VOCAB 128
#define NBS (B_SZ*SEQ)       // 1536
#define EPSV 1e-5f

static inline int cdiv_h(int a, int b){ return (a + b - 1) / b; }

__device__ __forceinline__ float silu_f(float x){ return x / (1.0f + expf(-x)); }

// ---------------- permute: x (B,S,F,C,E) -> h (B*S, C*F*E) with d=(c*F+f)*E+e
__global__ void k_permute(const float* __restrict__ x, float* __restrict__ h){
  int idx = blockIdx.x * 256 + threadIdx.x;
  if (idx >= NBS * D_MODEL) return;
  int d = idx % D_MODEL;
  int row = idx / D_MODEL;
  int e = d % 5;
  int f = (d / 5) % 5;
  int c = d / 25;
  h[idx] = x[(((size_t)row * 5 + f) * 62 + c) * 5 + e];
}

// ---------------- rmsnorm: one block per row
__global__ void k_rmsnorm(const float* __restrict__ in, const float* __restrict__ w,
                          float* __restrict__ out, int D){
  int row = blockIdx.x;
  const float* xr = in + (size_t)row * D;
  float ss = 0.f;
  for (int i = threadIdx.x; i < D; i += blockDim.x){ float v = xr[i]; ss = fmaf(v, v, ss); }
  __shared__ float red[4];
  __shared__ float sscale;
  int lane = threadIdx.x & 63, wv = threadIdx.x >> 6;
  #pragma unroll
  for (int o = 32; o > 0; o >>= 1) ss += __shfl_down(ss, o, 64);
  if (lane == 0) red[wv] = ss;
  __syncthreads();
  if (threadIdx.x == 0){
    float t = red[0] + red[1] + red[2] + red[3];
    sscale = 1.0f / sqrtf(t / (float)D + EPSV);
  }
  __syncthreads();
  float sc = sscale;
  for (int i = threadIdx.x; i < D; i += blockDim.x)
    out[(size_t)row * D + i] = xr[i] * sc * w[i];
}

// ---------------- generic NT GEMM: C[M,N] = A[M,K] * B[N,K]^T (+ addC)
#define BM 64
#define BN 64
#define BK 16

__global__ __launch_bounds__(256, 2)
void k_gemm_nt(const float* __restrict__ A, const float* __restrict__ B,
               float* __restrict__ C, const float* __restrict__ addC,
               int M, int N, int K){
  __shared__ float As[BK][BM + 4];
  __shared__ float Bs[BK][BN + 4];
  const int bm = blockIdx.y * BM, bn = blockIdx.x * BN;
  const int tid = threadIdx.x;
  const int tm = (tid & 15) * 4;
  const int tn = (tid >> 4) * 4;
  const int lr = tid >> 2;        // 0..63
  const int lc = (tid & 3) * 4;   // 0,4,8,12
  float acc[4][4] = {{0.f,0.f,0.f,0.f},{0.f,0.f,0.f,0.f},{0.f,0.f,0.f,0.f},{0.f,0.f,0.f,0.f}};
  const float* Arow = A + (size_t)(bm + lr) * K;
  const float* Brow = B + (size_t)(bn + lr) * K;
  const bool a_ok = (bm + lr) < M;
  const bool b_ok = (bn + lr) < N;
  for (int k0 = 0; k0 < K; k0 += BK){
    #pragma unroll
    for (int j = 0; j < 4; j++){
      int kk = k0 + lc + j;
      As[lc + j][lr] = (a_ok && kk < K) ? Arow[kk] : 0.f;
      Bs[lc + j][lr] = (b_ok && kk < K) ? Brow[kk] : 0.f;
    }
    __syncthreads();
    #pragma unroll
    for (int kk = 0; kk < BK; kk++){
      float av[4], bv[4];
      #pragma unroll
      for (int i = 0; i < 4; i++) av[i] = As[kk][tm + i];
      #pragma unroll
      for (int j = 0; j < 4; j++) bv[j] = Bs[kk][tn + j];
      #pragma unroll
      for (int i = 0; i < 4; i++)
        #pragma unroll
        for (int j = 0; j < 4; j++)
          acc[i][j] = fmaf(av[i], bv[j], acc[i][j]);
    }
    __syncthreads();
  }
  #pragma unroll
  for (int i = 0; i < 4; i++){
    int m = bm + tm + i; if (m >= M) continue;
    #pragma unroll
    for (int j = 0; j < 4; j++){
      int n = bn + tn + j; if (n >= N) continue;
      float v = acc[i][j];
      if (addC) v += addC[(size_t)m * N + n];
      C[(size_t)m * N + n] = v;
    }
  }
}

// ---------------- causal depthwise conv (S=3, k=4) + silu. xz cols [0,ED) are x_in.
__global__ void k_conv_silu(const float* __restrict__ xz, const float* __restrict__ cw,
                            const float* __restrict__ cb, float* __restrict__ xc){
  int idx = blockIdx.x * 256 + threadIdx.x;
  if (idx >= B_SZ * ED) return;
  int ch = idx % ED;
  int b  = idx / ED;
  const float* base = xz + (size_t)b * SEQ * (2 * ED) + ch;
  float x0 = base[0];
  float x1 = base[2 * ED];
  float x2 = base[4 * ED];
  const float* w = cw + (size_t)ch * 4;
  float w1 = w[1], w2 = w[2], w3 = w[3];
  float bb = cb[ch];
  float y0 = fmaf(w3, x0, bb);
  float y1 = fmaf(w2, x0, fmaf(w3, x1, bb));
  float y2 = fmaf(w1, x0, fmaf(w2, x1, fmaf(w3, x2, bb)));
  size_t o = (size_t)b * SEQ * ED + ch;
  xc[o]            = silu_f(y0);
  xc[o + ED]       = silu_f(y1);
  xc[o + 2 * ED]   = silu_f(y2);
}

// ---------------- fused dt_proj + softplus + SSM scan + D skip + z gate.
// Reads xc, writes gated y in-place into xc.
__global__ __launch_bounds__(256)
void k_scan(const float* __restrict__ dbc, const float* __restrict__ dtw,
            const float* __restrict__ dtb, const float* __restrict__ A_log,
            const float* __restrict__ Dp, const float* __restrict__ xz,
            float* __restrict__ xc){
  __shared__ float sdbc[SEQ][DBC_R];
  int b = blockIdx.y;
  for (int i = threadIdx.x; i < SEQ * DBC_R; i += 256)
    sdbc[i / DBC_R][i % DBC_R] = dbc[(size_t)b * SEQ * DBC_R + i];
  __syncthreads();
  int ch = blockIdx.x * 256 + threadIdx.x;
  if (ch >= ED) return;

  // delta[t] = softplus(dot(dt_row[t], dtw[ch]) + dtb[ch])
  const float* wrow = dtw + (size_t)ch * DTR;
  float dlt[SEQ];
  float bias = dtb[ch];
  #pragma unroll
  for (int t = 0; t < SEQ; t++){
    float acc = bias;
    for (int r = 0; r < DTR; r++) acc = fmaf(sdbc[t][r], wrow[r], acc);
    dlt[t] = (acc > 20.f) ? acc : log1pf(expf(acc));
  }

  size_t xco = (size_t)b * SEQ * ED + ch;
  float xcv[SEQ] = { xc[xco], xc[xco + ED], xc[xco + 2 * ED] };
  float y[SEQ] = {0.f, 0.f, 0.f};
  const float* alr = A_log + (size_t)ch * NSTATE;
  #pragma unroll
  for (int n = 0; n < NSTATE; n++){
    float Av = -expf(alr[n]);
    float hs = 0.f;
    #pragma unroll
    for (int t = 0; t < SEQ; t++){
      float dA = expf(dlt[t] * Av);
      hs = fmaf(dA, hs, dlt[t] * sdbc[t][DTR + n] * xcv[t]);
      y[t] = fmaf(hs, sdbc[t][DTR + NSTATE + n], y[t]);
    }
  }
  float dp = Dp[ch];
  const float* zbase = xz + (size_t)b * SEQ * (2 * ED) + ED + ch;
  #pragma unroll
  for (int t = 0; t < SEQ; t++){
    float z = zbase[(size_t)t * 2 * ED];
    float yy = fmaf(dp, xcv[t], y[t]);
    xc[xco + (size_t)t * ED] = yy * silu_f(z);
  }
}

// ---------------- logits stats (single block): mean, rstd over NBS*VOCAB
__global__ void k_stats(const float* __restrict__ logits, float* __restrict__ stats){
  float s = 0.f, ss = 0.f;
  for (int i = threadIdx.x; i < NBS * VOCAB; i += 1024){
    float v = logits[i]; s += v; ss = fmaf(v, v, ss);
  }
  __shared__ float rs[16], rss[16];
  #pragma unroll
  for (int o = 32; o > 0; o >>= 1){ s += __shfl_down(s, o, 64); ss += __shfl_down(ss, o, 64); }
  int lane = threadIdx.x & 63, wv = threadIdx.x >> 6;
  if (lane == 0){ rs[wv] = s; rss[wv] = ss; }
  __syncthreads();
  if (threadIdx.x == 0){
    float S1 = 0.f, S2 = 0.f;
    for (int i = 0; i < 16; i++){ S1 += rs[i]; S2 += rss[i]; }
    const float invN = 1.0f / (float)(NBS * VOCAB);
    float mean = S1 * invN;
    float var = S2 * invN - mean * mean;
    stats[0] = mean;
    stats[1] = 1.0f / sqrtf(var + EPSV);
  }
}

// ---------------- sumw[o] = sum_v emb_w[o,v]
__global__ void k_sumw(const float* __restrict__ emb_w, float* __restrict__ sumw){
  int o = threadIdx.x;
  const float* r = emb_w + (size_t)o * VOCAB;
  float s = 0.f;
  for (int v = 0; v < VOCAB; v++) s += r[v];
  sumw[o] = s;
}

// ---------------- final: out[b,f,s,o]
__global__ void k_final(const float* __restrict__ proj, const float* __restrict__ sumw,
                        const float* __restrict__ stats, const float* __restrict__ bnw,
                        const float* __restrict__ bnb, const float* __restrict__ embb,
                        float* __restrict__ out){
  size_t idx = (size_t)blockIdx.x * 256 + threadIdx.x;
  if (idx >= (size_t)B_SZ * 5 * SEQ * 256) return;
  int o = idx & 255;
  size_t r = idx >> 8;          // (b*5+f)*SEQ + s
  int s = (int)(r % SEQ);
  size_t bf = r / SEQ;
  int f = (int)(bf % 5);
  size_t b = bf / 5;
  float mean = stats[0], rstd = stats[1];
  float p = proj[((b * SEQ) + s) * 256 + o];
  float sw = sumw[o];
  out[idx] = bnw[f] * rstd * (p - mean * sw) + bnb[f] * sw + embb[o];
}

extern "C" void kernel_launch(void* const* d_in, const int* in_sizes, int n_in,
                              void* d_out, int out_size, void* d_ws, size_t ws_size,
                              hipStream_t stream) {
  const float* x          = (const float*)d_in[0];
  const float* in_proj_w  = (const float*)d_in[1];
  const float* conv_w     = (const float*)d_in[2];
  const float* conv_b     = (const float*)d_in[3];
  const float* x_proj_w   = (const float*)d_in[4];
  const float* dt_proj_w  = (const float*)d_in[5];
  const float* dt_proj_b  = (const float*)d_in[6];
  const float* A_log      = (const float*)d_in[7];
  const float* D_param    = (const float*)d_in[8];
  const float* out_proj_w = (const float*)d_in[9];
  const float* norm_w     = (const float*)d_in[10];
  const float* normf_w    = (const float*)d_in[11];
  const float* lm_head_w  = (const float*)d_in[12];
  const float* bn_w       = (const float*)d_in[13];
  const float* bn_b       = (const float*)d_in[14];
  const float* emb_w      = (const float*)d_in[15];
  const float* emb_b      = (const float*)d_in[16];

  float* ws = (float*)d_ws;
  float* h      = ws;
  float* hn     = h      + (size_t)NBS * D_MODEL;
  float* xz     = hn     + (size_t)NBS * D_MODEL;
  float* xc     = xz     + (size_t)NBS * 2 * ED;
  float* dbc    = xc     + (size_t)NBS * ED;
  float* logits = dbc    + (size_t)NBS * DBC_R;
  float* proj   = logits + (size_t)NBS * VOCAB;
  float* sumw   = proj   + (size_t)NBS * 256;
  float* stats  = sumw   + 256;
  size_t need_f = (size_t)(stats + 2 - ws);
  if (ws_size < need_f * sizeof(float)) return;

  // h = permuted input
  k_permute<<<cdiv_h(NBS * D_MODEL, 256), 256, 0, stream>>>(x, h);

  for (int l = 0; l < 2; l++){
    const float* ipw = in_proj_w  + (size_t)l * 2 * ED * D_MODEL;
    const float* cw  = conv_w     + (size_t)l * ED * 4;
    const float* cb  = conv_b     + (size_t)l * ED;
    const float* xpw = x_proj_w   + (size_t)l * DBC_R * ED;
    const float* dtw = dt_proj_w  + (size_t)l * ED * DTR;
    const float* dtb = dt_proj_b  + (size_t)l * ED;
    const float* al  = A_log      + (size_t)l * ED * NSTATE;
    const float* dp  = D_param    + (size_t)l * ED;
    const float* opw = out_proj_w + (size_t)l * D_MODEL * ED;
    const float* nw  = norm_w     + (size_t)l * D_MODEL;

    k_rmsnorm<<<NBS, 256, 0, stream>>>(h, nw, hn, D_MODEL);
    // xz = hn @ in_proj^T : M=NBS, N=2*ED, K=D_MODEL
    k_gemm_nt<<<dim3(cdiv_h(2 * ED, BN), cdiv_h(NBS, BM)), 256, 0, stream>>>(
        hn, ipw, xz, nullptr, NBS, 2 * ED, D_MODEL);
    k_conv_silu<<<cdiv_h(B_SZ * ED, 256), 256, 0, stream>>>(xz, cw, cb, xc);
    // dbc = xc @ x_proj^T : M=NBS, N=129, K=ED
    k_gemm_nt<<<dim3(cdiv_h(DBC_R, BN), cdiv_h(NBS, BM)), 256, 0, stream>>>(
        xc, xpw, dbc, nullptr, NBS, DBC_R, ED);
    // fused dt_proj + scan + gate (in-place on xc)
    k_scan<<<dim3(cdiv_h(ED, 256), B_SZ), 256, 0, stream>>>(dbc, dtw, dtb, al, dp, xz, xc);
    // h = h + xc @ out_proj^T : M=NBS, N=D_MODEL, K=ED
    k_gemm_nt<<<dim3(cdiv_h(D_MODEL, BN), cdiv_h(NBS, BM)), 256, 0, stream>>>(
        xc, opw, h, h, NBS, D_MODEL, ED);
  }

  // final norm + lm head
  k_rmsnorm<<<NBS, 256, 0, stream>>>(h, normf_w, hn, D_MODEL);
  k_gemm_nt<<<dim3(cdiv_h(VOCAB, BN), cdiv_h(NBS, BM)), 256, 0, stream>>>(
      hn, lm_head_w, logits, nullptr, NBS, VOCAB, D_MODEL);
  k_stats<<<1, 1024, 0, stream>>>(logits, stats);
  k_sumw<<<1, 256, 0, stream>>>(emb_w, sumw);
  // proj = logits @ emb_w^T : M=NBS, N=256, K=128
  k_gemm_nt<<<dim3(cdiv_h(256, BN), cdiv_h(NBS, BM)), 256, 0, stream>>>(
      logits, emb_w, proj, nullptr, NBS, 256, VOCAB);
  k_final<<<cdiv_h(B_SZ * 5 * SEQ * 256, 256), 256, 0, stream>>>(
      proj, sumw, stats, bn_w, bn_b, emb_b, (float*)d_out);
}

// Round 2
// 1285.400 us; speedup vs baseline: 3.2419x; 3.2419x over previous
//
#include <hip/hip_runtime.h>
#include <hip/hip_bf16.h>
#include <math.h>

#define B_SZ 512
#define SEQ 3
#define D_MODEL 1550
#define ED 3100
#define NSTATE 16
#define DTR 97
#define DBC_R 129   // DTR + 2*NSTATE
#define VOCAB 128
#define NBS (B_SZ*SEQ)       // 1536
#define EPSV 1e-5f

// padded dims
#define KD 1600     // D_MODEL -> 64*25
#define KE 3136     // ED -> 64*49
#define NIP 6272    // 2*ED=6200 -> 49*128
#define NXP 256     // 129 -> 2*128
#define NOP 1664    // 1550 -> 13*128
#define DBC_LD 256

static inline int cdiv_h(int a, int b){ return (a + b - 1) / b; }

__device__ __forceinline__ float silu_f(float x){ return x / (1.0f + expf(-x)); }

using bf16x8 = __attribute__((ext_vector_type(8))) short;
using f32x4  = __attribute__((ext_vector_type(4))) float;

__device__ __forceinline__ void gload16(const void* g, void* l){
  __builtin_amdgcn_global_load_lds(
      (const __attribute__((address_space(1))) unsigned int*)g,
      (__attribute__((address_space(3))) unsigned int*)l,
      16, 0, 0);
}

// ---------------- permute: x (B,S,F,C,E) -> h (B*S, C*F*E) with d=(c*F+f)*E+e
__global__ void k_permute(const float* __restrict__ x, float* __restrict__ h){
  int idx = blockIdx.x * 256 + threadIdx.x;
  if (idx >= NBS * D_MODEL) return;
  int d = idx % D_MODEL;
  int row = idx / D_MODEL;
  int e = d % 5;
  int f = (d / 5) % 5;
  int c = d / 25;
  h[idx] = x[(((size_t)row * 5 + f) * 62 + c) * 5 + e];
}

// ---------------- rmsnorm -> bf16 padded row
__global__ void k_rmsnorm_bf16(const float* __restrict__ in, const float* __restrict__ w,
                               __hip_bfloat16* __restrict__ out, int D, int Kp){
  int row = blockIdx.x;
  const float* xr = in + (size_t)row * D;
  float ss = 0.f;
  for (int i = threadIdx.x; i < D; i += blockDim.x){ float v = xr[i]; ss = fmaf(v, v, ss); }
  __shared__ float red[4];
  __shared__ float sscale;
  int lane = threadIdx.x & 63, wv = threadIdx.x >> 6;
  #pragma unroll
  for (int o = 32; o > 0; o >>= 1) ss += __shfl_down(ss, o, 64);
  if (lane == 0) red[wv] = ss;
  __syncthreads();
  if (threadIdx.x == 0){
    float t = red[0] + red[1] + red[2] + red[3];
    sscale = 1.0f / sqrtf(t / (float)D + EPSV);
  }
  __syncthreads();
  float sc = sscale;
  __hip_bfloat16* orow = out + (size_t)row * Kp;
  for (int i = threadIdx.x; i < Kp; i += blockDim.x){
    float v = (i < D) ? xr[i] * sc * w[i] : 0.f;
    orow[i] = __float2bfloat16(v);
  }
}

// ---------------- cast + pad weight: src fp32 [N][K] -> dst bf16 [Np][Kp]
__global__ void k_cast_pad(const float* __restrict__ src, __hip_bfloat16* __restrict__ dst,
                           int N, int K, int Kp, int Np){
  size_t i4 = ((size_t)blockIdx.x * 256 + threadIdx.x) * 4;
  if (i4 >= (size_t)Np * Kp) return;
  int row = (int)(i4 / Kp);
  int col = (int)(i4 % Kp);
  const float* srow = src + (size_t)row * K;
  #pragma unroll
  for (int j = 0; j < 4; j++){
    int c = col + j;
    float v = (row < N && c < K) ? srow[c] : 0.f;
    dst[i4 + j] = __float2bfloat16(v);
  }
}

// ---------------- bf16 MFMA NT GEMM (m97 structure): C[M,Nld] = A[M,Kp] * B[Npad,Kp]^T
// A,B bf16 padded (Kp mult of 32). M mult of 128. Writes cols < Nreal. addC optional.
__global__ __launch_bounds__(256)
void k_gemm_bf16(const __hip_bfloat16* __restrict__ A, const __hip_bfloat16* __restrict__ B,
                 float* C, const float* addC, int Kp, int Nld, int Nreal){
  __shared__ short Al[4096];   // 128 x 32 bf16
  __shared__ short Bl[4096];
  const int bm = blockIdx.y * 128, bn = blockIdx.x * 128;
  const int t = threadIdx.x;
  const short* Ab = (const short*)A;
  const short* Bb = (const short*)B;
  const short* ga0 = Ab + (size_t)(bm + (t >> 2)) * Kp + (t & 3) * 8;
  const short* ga1 = Ab + (size_t)(bm + 64 + (t >> 2)) * Kp + (t & 3) * 8;
  const short* gb0 = Bb + (size_t)(bn + (t >> 2)) * Kp + (t & 3) * 8;
  const short* gb1 = Bb + (size_t)(bn + 64 + (t >> 2)) * Kp + (t & 3) * 8;
  short* la0 = Al + t * 8;
  short* la1 = Al + 2048 + t * 8;
  short* lb0 = Bl + t * 8;
  short* lb1 = Bl + 2048 + t * 8;

  const int l = t & 63;
  const int wid = t >> 6;
  const int wr = wid >> 1, wc = wid & 1;
  const int fr = l & 15;
  const int ko = (l >> 4) * 8;

  f32x4 acc[4][4] = {};

  for (int k0 = 0; k0 < Kp; k0 += 32){
    gload16(ga0 + k0, la0);
    gload16(ga1 + k0, la1);
    gload16(gb0 + k0, lb0);
    gload16(gb1 + k0, lb1);
    __syncthreads();
    bf16x8 af[4], bfr[4];
    #pragma unroll
    for (int m = 0; m < 4; m++)
      af[m] = *(const bf16x8*)&Al[(wr * 64 + m * 16 + fr) * 32 + ko];
    #pragma unroll
    for (int n = 0; n < 4; n++)
      bfr[n] = *(const bf16x8*)&Bl[(wc * 64 + n * 16 + fr) * 32 + ko];
    #pragma unroll
    for (int m = 0; m < 4; m++)
      #pragma unroll
      for (int n = 0; n < 4; n++)
        acc[m][n] = __builtin_amdgcn_mfma_f32_16x16x32_bf16(af[m], bfr[n], acc[m][n], 0, 0, 0);
    __syncthreads();
  }

  const int r0 = (l >> 4) * 4;
  #pragma unroll
  for (int m = 0; m < 4; m++){
    #pragma unroll
    for (int n = 0; n < 4; n++){
      int col = bn + wc * 64 + n * 16 + fr;
      if (col < Nreal){
        size_t base = (size_t)(bm + wr * 64 + m * 16 + r0) * Nld + col;
        #pragma unroll
        for (int j = 0; j < 4; j++){
          float v = acc[m][n][j];
          if (addC) v += addC[base + (size_t)j * Nld];
          C[base + (size_t)j * Nld] = v;
        }
      }
    }
  }
}

// ---------------- fp32 NT GEMM (small epilogue GEMM only)
#define BM 64
#define BN 64
#define BK 16
__global__ __launch_bounds__(256, 2)
void k_gemm_nt(const float* __restrict__ A, const float* __restrict__ B,
               float* C, const float* addC, int M, int N, int K){
  __shared__ float As[BK][BM + 4];
  __shared__ float Bs[BK][BN + 4];
  const int bm = blockIdx.y * BM, bn = blockIdx.x * BN;
  const int tid = threadIdx.x;
  const int tm = (tid & 15) * 4;
  const int tn = (tid >> 4) * 4;
  const int lr = tid >> 2;
  const int lc = (tid & 3) * 4;
  float acc[4][4] = {{0.f,0.f,0.f,0.f},{0.f,0.f,0.f,0.f},{0.f,0.f,0.f,0.f},{0.f,0.f,0.f,0.f}};
  const float* Arow = A + (size_t)(bm + lr) * K;
  const float* Brow = B + (size_t)(bn + lr) * K;
  const bool a_ok = (bm + lr) < M;
  const bool b_ok = (bn + lr) < N;
  for (int k0 = 0; k0 < K; k0 += BK){
    #pragma unroll
    for (int j = 0; j < 4; j++){
      int kk = k0 + lc + j;
      As[lc + j][lr] = (a_ok && kk < K) ? Arow[kk] : 0.f;
      Bs[lc + j][lr] = (b_ok && kk < K) ? Brow[kk] : 0.f;
    }
    __syncthreads();
    #pragma unroll
    for (int kk = 0; kk < BK; kk++){
      float av[4], bv[4];
      #pragma unroll
      for (int i = 0; i < 4; i++) av[i] = As[kk][tm + i];
      #pragma unroll
      for (int j = 0; j < 4; j++) bv[j] = Bs[kk][tn + j];
      #pragma unroll
      for (int i = 0; i < 4; i++)
        #pragma unroll
        for (int j = 0; j < 4; j++)
          acc[i][j] = fmaf(av[i], bv[j], acc[i][j]);
    }
    __syncthreads();
  }
  #pragma unroll
  for (int i = 0; i < 4; i++){
    int m = bm + tm + i; if (m >= M) continue;
    #pragma unroll
    for (int j = 0; j < 4; j++){
      int n = bn + tn + j; if (n >= N) continue;
      float v = acc[i][j];
      if (addC) v += addC[(size_t)m * N + n];
      C[(size_t)m * N + n] = v;
    }
  }
}

// ---------------- causal depthwise conv (S=3, k=4) + silu
// xz fp32 stride NIP; x part cols [0,ED), z cols [ED, 2*ED)
__global__ void k_conv_silu(const float* __restrict__ xz, const float* __restrict__ cw,
                            const float* __restrict__ cb, float* __restrict__ xc_f,
                            __hip_bfloat16* __restrict__ xc_b){
  int idx = blockIdx.x * 256 + threadIdx.x;
  if (idx >= B_SZ * KE) return;
  int ch = idx % KE;
  int b  = idx / KE;
  size_t ob = (size_t)b * SEQ * KE + ch;
  if (ch >= ED){
    __hip_bfloat16 z = __float2bfloat16(0.f);
    xc_b[ob] = z; xc_b[ob + KE] = z; xc_b[ob + 2 * KE] = z;
    return;
  }
  const float* base = xz + (size_t)b * SEQ * NIP + ch;
  float x0 = base[0];
  float x1 = base[NIP];
  float x2 = base[2 * NIP];
  const float* w = cw + (size_t)ch * 4;
  float w1 = w[1], w2 = w[2], w3 = w[3];
  float bb = cb[ch];
  float s0 = silu_f(fmaf(w3, x0, bb));
  float s1 = silu_f(fmaf(w2, x0, fmaf(w3, x1, bb)));
  float s2 = silu_f(fmaf(w1, x0, fmaf(w2, x1, fmaf(w3, x2, bb))));
  size_t of = (size_t)b * SEQ * ED + ch;
  xc_f[of]          = s0;
  xc_f[of + ED]     = s1;
  xc_f[of + 2 * ED] = s2;
  xc_b[ob]          = __float2bfloat16(s0);
  xc_b[ob + KE]     = __float2bfloat16(s1);
  xc_b[ob + 2 * KE] = __float2bfloat16(s2);
}

// ---------------- fused dt_proj + softplus + SSM scan + D skip + z gate -> bf16 padded
__global__ __launch_bounds__(256)
void k_scan(const float* __restrict__ dbc, const float* __restrict__ dtw,
            const float* __restrict__ dtb, const float* __restrict__ A_log,
            const float* __restrict__ Dp, const float* __restrict__ xz,
            const float* __restrict__ xc_f, __hip_bfloat16* __restrict__ xc_b){
  __shared__ float sdbc[SEQ][DBC_R];
  int b = blockIdx.y;
  for (int i = threadIdx.x; i < SEQ * DBC_R; i += 256)
    sdbc[i / DBC_R][i % DBC_R] = dbc[(size_t)b * SEQ * DBC_LD + (i / DBC_R) * DBC_LD + (i % DBC_R)];
  __syncthreads();
  int ch = blockIdx.x * 256 + threadIdx.x;
  if (ch >= ED) return;

  const float* wrow = dtw + (size_t)ch * DTR;
  float dlt[SEQ];
  float bias = dtb[ch];
  #pragma unroll
  for (int t = 0; t < SEQ; t++){
    float acc = bias;
    for (int r = 0; r < DTR; r++) acc = fmaf(sdbc[t][r], wrow[r], acc);
    dlt[t] = (acc > 20.f) ? acc : log1pf(expf(acc));
  }

  size_t of = (size_t)b * SEQ * ED + ch;
  float xcv[SEQ] = { xc_f[of], xc_f[of + ED], xc_f[of + 2 * ED] };
  float y[SEQ] = {0.f, 0.f, 0.f};
  const float* alr = A_log + (size_t)ch * NSTATE;
  #pragma unroll
  for (int n = 0; n < NSTATE; n++){
    float Av = -expf(alr[n]);
    float hs = 0.f;
    #pragma unroll
    for (int t = 0; t < SEQ; t++){
      float dA = expf(dlt[t] * Av);
      hs = fmaf(dA, hs, dlt[t] * sdbc[t][DTR + n] * xcv[t]);
      y[t] = fmaf(hs, sdbc[t][DTR + NSTATE + n], y[t]);
    }
  }
  float dp = Dp[ch];
  const float* zbase = xz + (size_t)b * SEQ * NIP + ED + ch;
  size_t ob = (size_t)b * SEQ * KE + ch;
  #pragma unroll
  for (int t = 0; t < SEQ; t++){
    float z = zbase[(size_t)t * NIP];
    float yy = fmaf(dp, xcv[t], y[t]);
    xc_b[ob + (size_t)t * KE] = __float2bfloat16(yy * silu_f(z));
  }
}

// ---------------- logits stats (single block)
__global__ void k_stats(const float* __restrict__ logits, float* __restrict__ stats){
  float s = 0.f, ss = 0.f;
  for (int i = threadIdx.x; i < NBS * VOCAB; i += 1024){
    float v = logits[i]; s += v; ss = fmaf(v, v, ss);
  }
  __shared__ float rs[16], rss[16];
  #pragma unroll
  for (int o = 32; o > 0; o >>= 1){ s += __shfl_down(s, o, 64); ss += __shfl_down(ss, o, 64); }
  int lane = threadIdx.x & 63, wv = threadIdx.x >> 6;
  if (lane == 0){ rs[wv] = s; rss[wv] = ss; }
  __syncthreads();
  if (threadIdx.x == 0){
    float S1 = 0.f, S2 = 0.f;
    for (int i = 0; i < 16; i++){ S1 += rs[i]; S2 += rss[i]; }
    const float invN = 1.0f / (float)(NBS * VOCAB);
    float mean = S1 * invN;
    float var = S2 * invN - mean * mean;
    stats[0] = mean;
    stats[1] = 1.0f / sqrtf(var + EPSV);
  }
}

__global__ void k_sumw(const float* __restrict__ emb_w, float* __restrict__ sumw){
  int o = threadIdx.x;
  const float* r = emb_w + (size_t)o * VOCAB;
  float s = 0.f;
  for (int v = 0; v < VOCAB; v++) s += r[v];
  sumw[o] = s;
}

__global__ void k_final(const float* __restrict__ proj, const float* __restrict__ sumw,
                        const float* __restrict__ stats, const float* __restrict__ bnw,
                        const float* __restrict__ bnb, const float* __restrict__ embb,
                        float* __restrict__ out){
  size_t idx = (size_t)blockIdx.x * 256 + threadIdx.x;
  if (idx >= (size_t)B_SZ * 5 * SEQ * 256) return;
  int o = idx & 255;
  size_t r = idx >> 8;
  int s = (int)(r % SEQ);
  size_t bf = r / SEQ;
  int f = (int)(bf % 5);
  size_t b = bf / 5;
  float mean = stats[0], rstd = stats[1];
  float p = proj[((b * SEQ) + s) * 256 + o];
  float sw = sumw[o];
  out[idx] = bnw[f] * rstd * (p - mean * sw) + bnb[f] * sw + embb[o];
}

extern "C" void kernel_launch(void* const* d_in, const int* in_sizes, int n_in,
                              void* d_out, int out_size, void* d_ws, size_t ws_size,
                              hipStream_t stream) {
  const float* x          = (const float*)d_in[0];
  const float* in_proj_w  = (const float*)d_in[1];
  const float* conv_w     = (const float*)d_in[2];
  const float* conv_b     = (const float*)d_in[3];
  const float* x_proj_w   = (const float*)d_in[4];
  const float* dt_proj_w  = (const float*)d_in[5];
  const float* dt_proj_b  = (const float*)d_in[6];
  const float* A_log      = (const float*)d_in[7];
  const float* D_param    = (const float*)d_in[8];
  const float* out_proj_w = (const float*)d_in[9];
  const float* norm_w     = (const float*)d_in[10];
  const float* normf_w    = (const float*)d_in[11];
  const float* lm_head_w  = (const float*)d_in[12];
  const float* bn_w       = (const float*)d_in[13];
  const float* bn_b       = (const float*)d_in[14];
  const float* emb_w      = (const float*)d_in[15];
  const float* emb_b      = (const float*)d_in[16];

  float* ws = (float*)d_ws;
  float* h      = ws;                                   // NBS*D_MODEL
  float* xz     = h      + (size_t)NBS * D_MODEL;       // NBS*NIP
  float* xc_f   = xz     + (size_t)NBS * NIP;           // NBS*ED
  float* dbc    = xc_f   + (size_t)NBS * ED;            // NBS*DBC_LD
  float* logits = dbc    + (size_t)NBS * DBC_LD;        // NBS*VOCAB
  float* proj   = logits + (size_t)NBS * VOCAB;         // NBS*256
  float* sumw   = proj   + (size_t)NBS * 256;           // 256
  float* stats  = sumw   + 256;                         // 4
  __hip_bfloat16* hn_b = (__hip_bfloat16*)(stats + 4);  // NBS*KD
  __hip_bfloat16* xc_b = hn_b + (size_t)NBS * KD;       // NBS*KE
  __hip_bfloat16* wb   = xc_b + (size_t)NBS * KE;       // NIP*KD (max weight)
  size_t need = (size_t)((char*)(wb + (size_t)NIP * KD) - (char*)ws);
  if (ws_size < need) return;

  k_permute<<<cdiv_h(NBS * D_MODEL, 256), 256, 0, stream>>>(x, h);

  for (int l = 0; l < 2; l++){
    const float* ipw = in_proj_w  + (size_t)l * 2 * ED * D_MODEL;
    const float* cw  = conv_w     + (size_t)l * ED * 4;
    const float* cb  = conv_b     + (size_t)l * ED;
    const float* xpw = x_proj_w   + (size_t)l * DBC_R * ED;
    const float* dtw = dt_proj_w  + (size_t)l * ED * DTR;
    const float* dtb = dt_proj_b  + (size_t)l * ED;
    const float* al  = A_log      + (size_t)l * ED * NSTATE;
    const float* dp  = D_param    + (size_t)l * ED;
    const float* opw = out_proj_w + (size_t)l * D_MODEL * ED;
    const float* nw  = norm_w     + (size_t)l * D_MODEL;

    k_rmsnorm_bf16<<<NBS, 256, 0, stream>>>(h, nw, hn_b, D_MODEL, KD);

    // in_proj: xz[1536,6272] = hn_b[1536,1600] @ ipw_b[6272,1600]^T
    k_cast_pad<<<cdiv_h(NIP * KD / 4, 256), 256, 0, stream>>>(ipw, wb, 2 * ED, D_MODEL, KD, NIP);
    k_gemm_bf16<<<dim3(NIP / 128, NBS / 128), 256, 0, stream>>>(hn_b, wb, xz, nullptr, KD, NIP, NIP);

    k_conv_silu<<<cdiv_h(B_SZ * KE, 256), 256, 0, stream>>>(xz, cw, cb, xc_f, xc_b);

    // x_proj: dbc[1536,256] = xc_b[1536,3136] @ xpw_b[256,3136]^T
    k_cast_pad<<<cdiv_h(NXP * KE / 4, 256), 256, 0, stream>>>(xpw, wb, DBC_R, ED, KE, NXP);
    k_gemm_bf16<<<dim3(NXP / 128, NBS / 128), 256, 0, stream>>>(xc_b, wb, dbc, nullptr, KE, DBC_LD, DBC_LD);

    k_scan<<<dim3(cdiv_h(ED, 256), B_SZ), 256, 0, stream>>>(dbc, dtw, dtb, al, dp, xz, xc_f, xc_b);

    // out_proj: h[1536,1550] += xc_b[1536,3136] @ opw_b[1664,3136]^T
    k_cast_pad<<<cdiv_h(NOP * KE / 4, 256), 256, 0, stream>>>(opw, wb, D_MODEL, ED, KE, NOP);
    k_gemm_bf16<<<dim3(NOP / 128, NBS / 128), 256, 0, stream>>>(xc_b, wb, h, h, KE, D_MODEL, D_MODEL);
  }

  // final norm + lm head (bf16 MFMA)
  k_rmsnorm_bf16<<<NBS, 256, 0, stream>>>(h, normf_w, hn_b, D_MODEL, KD);
  k_cast_pad<<<cdiv_h(VOCAB * KD / 4, 256), 256, 0, stream>>>(lm_head_w, wb, VOCAB, D_MODEL, KD, VOCAB);
  k_gemm_bf16<<<dim3(1, NBS / 128), 256, 0, stream>>>(hn_b, wb, logits, nullptr, KD, VOCAB, VOCAB);

  k_stats<<<1, 1024, 0, stream>>>(logits, stats);
  k_sumw<<<1, 256, 0, stream>>>(emb_w, sumw);
  // proj = logits @ emb_w^T (fp32, small)
  k_gemm_nt<<<dim3(cdiv_h(256, BN), cdiv_h(NBS, BM)), 256, 0, stream>>>(
      logits, emb_w, proj, nullptr, NBS, 256, VOCAB);
  k_final<<<cdiv_h(B_SZ * 5 * SEQ * 256, 256), 256, 0, stream>>>(
      proj, sumw, stats, bn_w, bn_b, emb_b, (float*)d_out);
}

// Round 3
// 924.989 us; speedup vs baseline: 4.5050x; 1.3896x over previous
//
#include <hip/hip_runtime.h>
#include <hip/hip_bf16.h>
#include <math.h>

#define B_SZ 512
#define SEQ 3
#define D_MODEL 1550
#define ED 3100
#define NSTATE 16
#define DTR 97
#define DBC_R 129   // DTR + 2*NSTATE
#define VOCAB 128
#define NBS (B_SZ*SEQ)       // 1536
#define EPSV 1e-5f

// padded dims
#define KD 1600     // D_MODEL -> 64*25
#define KE 3136     // ED -> 64*49
#define NIP 6272    // 2*ED=6200 -> 49*128
#define NXP 256     // 129 -> 2*128
#define NOP 1664    // 1550 -> 13*128
#define NDT 3200    // ED -> 25*128 (dt gemm output cols)
#define KDT 128     // DTR -> 128
#define DBC_LD 256

static inline int cdiv_h(int a, int b){ return (a + b - 1) / b; }

__device__ __forceinline__ float silu_f(float x){ return x / (1.0f + expf(-x)); }

using bf16x8 = __attribute__((ext_vector_type(8))) short;
using f32x4  = __attribute__((ext_vector_type(4))) float;

__device__ __forceinline__ void gload16(const void* g, void* l){
  __builtin_amdgcn_global_load_lds(
      (const __attribute__((address_space(1))) unsigned int*)g,
      (__attribute__((address_space(3))) unsigned int*)l,
      16, 0, 0);
}

// ---------------- permute: x (B,S,F,C,E) -> h (B*S, C*F*E) with d=(c*F+f)*E+e
__global__ void k_permute(const float* __restrict__ x, float* __restrict__ h){
  int idx = blockIdx.x * 256 + threadIdx.x;
  if (idx >= NBS * D_MODEL) return;
  int d = idx % D_MODEL;
  int row = idx / D_MODEL;
  int e = d % 5;
  int f = (d / 5) % 5;
  int c = d / 25;
  h[idx] = x[(((size_t)row * 5 + f) * 62 + c) * 5 + e];
}

// ---------------- rmsnorm -> bf16 padded row
__global__ void k_rmsnorm_bf16(const float* __restrict__ in, const float* __restrict__ w,
                               __hip_bfloat16* __restrict__ out, int D, int Kp){
  int row = blockIdx.x;
  const float* xr = in + (size_t)row * D;
  float ss = 0.f;
  for (int i = threadIdx.x; i < D; i += blockDim.x){ float v = xr[i]; ss = fmaf(v, v, ss); }
  __shared__ float red[4];
  __shared__ float sscale;
  int lane = threadIdx.x & 63, wv = threadIdx.x >> 6;
  #pragma unroll
  for (int o = 32; o > 0; o >>= 1) ss += __shfl_down(ss, o, 64);
  if (lane == 0) red[wv] = ss;
  __syncthreads();
  if (threadIdx.x == 0){
    float t = red[0] + red[1] + red[2] + red[3];
    sscale = 1.0f / sqrtf(t / (float)D + EPSV);
  }
  __syncthreads();
  float sc = sscale;
  __hip_bfloat16* orow = out + (size_t)row * Kp;
  for (int i = threadIdx.x; i < Kp; i += blockDim.x){
    float v = (i < D) ? xr[i] * sc * w[i] : 0.f;
    orow[i] = __float2bfloat16(v);
  }
}

// ---------------- cast + pad weight: src fp32 [N][K] -> dst bf16 [Np][Kp]
__global__ void k_cast_pad(const float* __restrict__ src, __hip_bfloat16* __restrict__ dst,
                           int N, int K, int Kp, int Np){
  size_t i4 = ((size_t)blockIdx.x * 256 + threadIdx.x) * 4;
  if (i4 >= (size_t)Np * Kp) return;
  int row = (int)(i4 / Kp);
  int col = (int)(i4 % Kp);
  const float* srow = src + (size_t)row * K;
  #pragma unroll
  for (int j = 0; j < 4; j++){
    int c = col + j;
    float v = (row < N && c < K) ? srow[c] : 0.f;
    dst[i4 + j] = __float2bfloat16(v);
  }
}

// ---------------- cast dbc dt-cols -> bf16 [NBS][128]
__global__ void k_cast_dbc(const float* __restrict__ dbc, __hip_bfloat16* __restrict__ dst){
  int idx = blockIdx.x * 256 + threadIdx.x;
  if (idx >= NBS * KDT) return;
  int row = idx >> 7;
  int c = idx & 127;
  float v = (c < DTR) ? dbc[(size_t)row * DBC_LD + c] : 0.f;
  dst[idx] = __float2bfloat16(v);
}

// ---------------- A_t[n][ch] = -exp(A_log[ch][n])
__global__ void k_prepA(const float* __restrict__ A_log, float* __restrict__ A_t){
  int idx = blockIdx.x * 256 + threadIdx.x;
  if (idx >= NSTATE * ED) return;
  int n = idx / ED;
  int ch = idx % ED;
  A_t[idx] = -expf(A_log[(size_t)ch * NSTATE + n]);
}

// ---------------- bf16 MFMA NT GEMM (m97 structure): C[M,Nld] = A[M,Kp] * B[Npad,Kp]^T
__global__ __launch_bounds__(256)
void k_gemm_bf16(const __hip_bfloat16* __restrict__ A, const __hip_bfloat16* __restrict__ B,
                 float* C, const float* addC, int Kp, int Nld, int Nreal){
  __shared__ short Al[4096];   // 128 x 32 bf16
  __shared__ short Bl[4096];
  const int bm = blockIdx.y * 128, bn = blockIdx.x * 128;
  const int t = threadIdx.x;
  const short* Ab = (const short*)A;
  const short* Bb = (const short*)B;
  const short* ga0 = Ab + (size_t)(bm + (t >> 2)) * Kp + (t & 3) * 8;
  const short* ga1 = Ab + (size_t)(bm + 64 + (t >> 2)) * Kp + (t & 3) * 8;
  const short* gb0 = Bb + (size_t)(bn + (t >> 2)) * Kp + (t & 3) * 8;
  const short* gb1 = Bb + (size_t)(bn + 64 + (t >> 2)) * Kp + (t & 3) * 8;
  short* la0 = Al + t * 8;
  short* la1 = Al + 2048 + t * 8;
  short* lb0 = Bl + t * 8;
  short* lb1 = Bl + 2048 + t * 8;

  const int l = t & 63;
  const int wid = t >> 6;
  const int wr = wid >> 1, wc = wid & 1;
  const int fr = l & 15;
  const int ko = (l >> 4) * 8;

  f32x4 acc[4][4] = {};

  for (int k0 = 0; k0 < Kp; k0 += 32){
    gload16(ga0 + k0, la0);
    gload16(ga1 + k0, la1);
    gload16(gb0 + k0, lb0);
    gload16(gb1 + k0, lb1);
    __syncthreads();
    bf16x8 af[4], bfr[4];
    #pragma unroll
    for (int m = 0; m < 4; m++)
      af[m] = *(const bf16x8*)&Al[(wr * 64 + m * 16 + fr) * 32 + ko];
    #pragma unroll
    for (int n = 0; n < 4; n++)
      bfr[n] = *(const bf16x8*)&Bl[(wc * 64 + n * 16 + fr) * 32 + ko];
    #pragma unroll
    for (int m = 0; m < 4; m++)
      #pragma unroll
      for (int n = 0; n < 4; n++)
        acc[m][n] = __builtin_amdgcn_mfma_f32_16x16x32_bf16(af[m], bfr[n], acc[m][n], 0, 0, 0);
    __syncthreads();
  }

  const int r0 = (l >> 4) * 4;
  #pragma unroll
  for (int m = 0; m < 4; m++){
    #pragma unroll
    for (int n = 0; n < 4; n++){
      int col = bn + wc * 64 + n * 16 + fr;
      if (col < Nreal){
        size_t base = (size_t)(bm + wr * 64 + m * 16 + r0) * Nld + col;
        #pragma unroll
        for (int j = 0; j < 4; j++){
          float v = acc[m][n][j];
          if (addC) v += addC[base + (size_t)j * Nld];
          C[base + (size_t)j * Nld] = v;
        }
      }
    }
  }
}

// ---------------- fp32 NT GEMM (small epilogue GEMM only)
#define BM 64
#define BN 64
#define BK 16
__global__ __launch_bounds__(256, 2)
void k_gemm_nt(const float* __restrict__ A, const float* __restrict__ B,
               float* C, const float* addC, int M, int N, int K){
  __shared__ float As[BK][BM + 4];
  __shared__ float Bs[BK][BN + 4];
  const int bm = blockIdx.y * BM, bn = blockIdx.x * BN;
  const int tid = threadIdx.x;
  const int tm = (tid & 15) * 4;
  const int tn = (tid >> 4) * 4;
  const int lr = tid >> 2;
  const int lc = (tid & 3) * 4;
  float acc[4][4] = {{0.f,0.f,0.f,0.f},{0.f,0.f,0.f,0.f},{0.f,0.f,0.f,0.f},{0.f,0.f,0.f,0.f}};
  const float* Arow = A + (size_t)(bm + lr) * K;
  const float* Brow = B + (size_t)(bn + lr) * K;
  const bool a_ok = (bm + lr) < M;
  const bool b_ok = (bn + lr) < N;
  for (int k0 = 0; k0 < K; k0 += BK){
    #pragma unroll
    for (int j = 0; j < 4; j++){
      int kk = k0 + lc + j;
      As[lc + j][lr] = (a_ok && kk < K) ? Arow[kk] : 0.f;
      Bs[lc + j][lr] = (b_ok && kk < K) ? Brow[kk] : 0.f;
    }
    __syncthreads();
    #pragma unroll
    for (int kk = 0; kk < BK; kk++){
      float av[4], bv[4];
      #pragma unroll
      for (int i = 0; i < 4; i++) av[i] = As[kk][tm + i];
      #pragma unroll
      for (int j = 0; j < 4; j++) bv[j] = Bs[kk][tn + j];
      #pragma unroll
      for (int i = 0; i < 4; i++)
        #pragma unroll
        for (int j = 0; j < 4; j++)
          acc[i][j] = fmaf(av[i], bv[j], acc[i][j]);
    }
    __syncthreads();
  }
  #pragma unroll
  for (int i = 0; i < 4; i++){
    int m = bm + tm + i; if (m >= M) continue;
    #pragma unroll
    for (int j = 0; j < 4; j++){
      int n = bn + tn + j; if (n >= N) continue;
      float v = acc[i][j];
      if (addC) v += addC[(size_t)m * N + n];
      C[(size_t)m * N + n] = v;
    }
  }
}

// ---------------- causal depthwise conv (S=3, k=4) + silu
__global__ void k_conv_silu(const float* __restrict__ xz, const float* __restrict__ cw,
                            const float* __restrict__ cb, float* __restrict__ xc_f,
                            __hip_bfloat16* __restrict__ xc_b){
  int idx = blockIdx.x * 256 + threadIdx.x;
  if (idx >= B_SZ * KE) return;
  int ch = idx % KE;
  int b  = idx / KE;
  size_t ob = (size_t)b * SEQ * KE + ch;
  if (ch >= ED){
    __hip_bfloat16 z = __float2bfloat16(0.f);
    xc_b[ob] = z; xc_b[ob + KE] = z; xc_b[ob + 2 * KE] = z;
    return;
  }
  const float* base = xz + (size_t)b * SEQ * NIP + ch;
  float x0 = base[0];
  float x1 = base[NIP];
  float x2 = base[2 * NIP];
  const float* w = cw + (size_t)ch * 4;
  float w1 = w[1], w2 = w[2], w3 = w[3];
  float bb = cb[ch];
  float s0 = silu_f(fmaf(w3, x0, bb));
  float s1 = silu_f(fmaf(w2, x0, fmaf(w3, x1, bb)));
  float s2 = silu_f(fmaf(w1, x0, fmaf(w2, x1, fmaf(w3, x2, bb))));
  size_t of = (size_t)b * SEQ * ED + ch;
  xc_f[of]          = s0;
  xc_f[of + ED]     = s1;
  xc_f[of + 2 * ED] = s2;
  xc_b[ob]          = __float2bfloat16(s0);
  xc_b[ob + KE]     = __float2bfloat16(s1);
  xc_b[ob + 2 * KE] = __float2bfloat16(s2);
}

// ---------------- lean scan: softplus(delta_raw+bias) + SSM + D skip + z gate -> bf16
__global__ __launch_bounds__(256)
void k_scan2(const float* __restrict__ delta_raw, const float* __restrict__ dbc,
             const float* __restrict__ dtb, const float* __restrict__ A_t,
             const float* __restrict__ Dp, const float* __restrict__ xz,
             const float* __restrict__ xc_f, __hip_bfloat16* __restrict__ xc_b){
  __shared__ float sB[SEQ][NSTATE], sC[SEQ][NSTATE];
  int b = blockIdx.y;
  if (threadIdx.x < SEQ * 2 * NSTATE){
    int t = threadIdx.x / (2 * NSTATE), r = threadIdx.x % (2 * NSTATE);
    float v = dbc[(size_t)(b * SEQ + t) * DBC_LD + DTR + r];
    if (r < NSTATE) sB[t][r] = v; else sC[t][r - NSTATE] = v;
  }
  __syncthreads();
  int ch = blockIdx.x * 256 + threadIdx.x;
  if (ch >= ED) return;

  float bias = dtb[ch];
  float dlt[SEQ];
  #pragma unroll
  for (int t = 0; t < SEQ; t++){
    float acc = delta_raw[(size_t)(b * SEQ + t) * NDT + ch] + bias;
    dlt[t] = (acc > 20.f) ? acc : log1pf(expf(acc));
  }

  size_t of = (size_t)b * SEQ * ED + ch;
  float xcv[SEQ] = { xc_f[of], xc_f[of + ED], xc_f[of + 2 * ED] };
  float y[SEQ] = {0.f, 0.f, 0.f};
  #pragma unroll
  for (int n = 0; n < NSTATE; n++){
    float Av = A_t[(size_t)n * ED + ch];
    float hs = 0.f;
    #pragma unroll
    for (int t = 0; t < SEQ; t++){
      float dA = expf(dlt[t] * Av);
      hs = fmaf(dA, hs, dlt[t] * sB[t][n] * xcv[t]);
      y[t] = fmaf(hs, sC[t][n], y[t]);
    }
  }
  float dp = Dp[ch];
  const float* zbase = xz + (size_t)b * SEQ * NIP + ED + ch;
  size_t ob = (size_t)b * SEQ * KE + ch;
  #pragma unroll
  for (int t = 0; t < SEQ; t++){
    float z = zbase[(size_t)t * NIP];
    float yy = fmaf(dp, xcv[t], y[t]);
    xc_b[ob + (size_t)t * KE] = __float2bfloat16(yy * silu_f(z));
  }
}

// ---------------- logits stats (single block)
__global__ void k_stats(const float* __restrict__ logits, float* __restrict__ stats){
  float s = 0.f, ss = 0.f;
  for (int i = threadIdx.x; i < NBS * VOCAB; i += 1024){
    float v = logits[i]; s += v; ss = fmaf(v, v, ss);
  }
  __shared__ float rs[16], rss[16];
  #pragma unroll
  for (int o = 32; o > 0; o >>= 1){ s += __shfl_down(s, o, 64); ss += __shfl_down(ss, o, 64); }
  int lane = threadIdx.x & 63, wv = threadIdx.x >> 6;
  if (lane == 0){ rs[wv] = s; rss[wv] = ss; }
  __syncthreads();
  if (threadIdx.x == 0){
    float S1 = 0.f, S2 = 0.f;
    for (int i = 0; i < 16; i++){ S1 += rs[i]; S2 += rss[i]; }
    const float invN = 1.0f / (float)(NBS * VOCAB);
    float mean = S1 * invN;
    float var = S2 * invN - mean * mean;
    stats[0] = mean;
    stats[1] = 1.0f / sqrtf(var + EPSV);
  }
}

__global__ void k_sumw(const float* __restrict__ emb_w, float* __restrict__ sumw){
  int o = threadIdx.x;
  const float* r = emb_w + (size_t)o * VOCAB;
  float s = 0.f;
  for (int v = 0; v < VOCAB; v++) s += r[v];
  sumw[o] = s;
}

__global__ void k_final(const float* __restrict__ proj, const float* __restrict__ sumw,
                        const float* __restrict__ stats, const float* __restrict__ bnw,
                        const float* __restrict__ bnb, const float* __restrict__ embb,
                        float* __restrict__ out){
  size_t idx = (size_t)blockIdx.x * 256 + threadIdx.x;
  if (idx >= (size_t)B_SZ * 5 * SEQ * 256) return;
  int o = idx & 255;
  size_t r = idx >> 8;
  int s = (int)(r % SEQ);
  size_t bf = r / SEQ;
  int f = (int)(bf % 5);
  size_t b = bf / 5;
  float mean = stats[0], rstd = stats[1];
  float p = proj[((b * SEQ) + s) * 256 + o];
  float sw = sumw[o];
  out[idx] = bnw[f] * rstd * (p - mean * sw) + bnb[f] * sw + embb[o];
}

extern "C" void kernel_launch(void* const* d_in, const int* in_sizes, int n_in,
                              void* d_out, int out_size, void* d_ws, size_t ws_size,
                              hipStream_t stream) {
  const float* x          = (const float*)d_in[0];
  const float* in_proj_w  = (const float*)d_in[1];
  const float* conv_w     = (const float*)d_in[2];
  const float* conv_b     = (const float*)d_in[3];
  const float* x_proj_w   = (const float*)d_in[4];
  const float* dt_proj_w  = (const float*)d_in[5];
  const float* dt_proj_b  = (const float*)d_in[6];
  const float* A_log      = (const float*)d_in[7];
  const float* D_param    = (const float*)d_in[8];
  const float* out_proj_w = (const float*)d_in[9];
  const float* norm_w     = (const float*)d_in[10];
  const float* normf_w    = (const float*)d_in[11];
  const float* lm_head_w  = (const float*)d_in[12];
  const float* bn_w       = (const float*)d_in[13];
  const float* bn_b       = (const float*)d_in[14];
  const float* emb_w      = (const float*)d_in[15];
  const float* emb_b      = (const float*)d_in[16];

  float* ws = (float*)d_ws;
  float* h      = ws;                                   // NBS*D_MODEL
  float* xz     = h      + (size_t)NBS * D_MODEL;       // NBS*NIP
  float* xc_f   = xz     + (size_t)NBS * NIP;           // NBS*ED
  float* dbc    = xc_f   + (size_t)NBS * ED;            // NBS*DBC_LD
  float* logits = dbc    + (size_t)NBS * DBC_LD;        // NBS*VOCAB
  float* proj   = logits + (size_t)NBS * VOCAB;         // NBS*256
  float* sumw   = proj   + (size_t)NBS * 256;           // 256
  float* stats  = sumw   + 256;                         // 4
  float* delta_raw = stats + 4;                         // NBS*NDT
  float* A_t    = delta_raw + (size_t)NBS * NDT;        // NSTATE*ED
  __hip_bfloat16* hn_b  = (__hip_bfloat16*)(A_t + (size_t)NSTATE * ED); // NBS*KD
  __hip_bfloat16* xc_b  = hn_b + (size_t)NBS * KD;      // NBS*KE
  __hip_bfloat16* dbc_b = xc_b + (size_t)NBS * KE;      // NBS*KDT
  __hip_bfloat16* wb    = dbc_b + (size_t)NBS * KDT;    // NIP*KD (max weight)
  size_t need = (size_t)((char*)(wb + (size_t)NIP * KD) - (char*)ws);
  if (ws_size < need) return;

  k_permute<<<cdiv_h(NBS * D_MODEL, 256), 256, 0, stream>>>(x, h);

  for (int l = 0; l < 2; l++){
    const float* ipw = in_proj_w  + (size_t)l * 2 * ED * D_MODEL;
    const float* cw  = conv_w     + (size_t)l * ED * 4;
    const float* cb  = conv_b     + (size_t)l * ED;
    const float* xpw = x_proj_w   + (size_t)l * DBC_R * ED;
    const float* dtw = dt_proj_w  + (size_t)l * ED * DTR;
    const float* dtb = dt_proj_b  + (size_t)l * ED;
    const float* al  = A_log      + (size_t)l * ED * NSTATE;
    const float* dp  = D_param    + (size_t)l * ED;
    const float* opw = out_proj_w + (size_t)l * D_MODEL * ED;
    const float* nw  = norm_w     + (size_t)l * D_MODEL;

    k_rmsnorm_bf16<<<NBS, 256, 0, stream>>>(h, nw, hn_b, D_MODEL, KD);

    // in_proj: xz[1536,6272] = hn_b @ ipw_b^T
    k_cast_pad<<<cdiv_h(NIP * KD / 4, 256), 256, 0, stream>>>(ipw, wb, 2 * ED, D_MODEL, KD, NIP);
    k_gemm_bf16<<<dim3(NIP / 128, NBS / 128), 256, 0, stream>>>(hn_b, wb, xz, nullptr, KD, NIP, NIP);

    k_conv_silu<<<cdiv_h(B_SZ * KE, 256), 256, 0, stream>>>(xz, cw, cb, xc_f, xc_b);

    // x_proj: dbc[1536,256] = xc_b @ xpw_b^T
    k_cast_pad<<<cdiv_h(NXP * KE / 4, 256), 256, 0, stream>>>(xpw, wb, DBC_R, ED, KE, NXP);
    k_gemm_bf16<<<dim3(NXP / 128, NBS / 128), 256, 0, stream>>>(xc_b, wb, dbc, nullptr, KE, DBC_LD, DBC_LD);

    // dt_proj as GEMM: delta_raw[1536,3200] = dbc_b[1536,128] @ dtw_b[3200,128]^T
    k_cast_dbc<<<cdiv_h(NBS * KDT, 256), 256, 0, stream>>>(dbc, dbc_b);
    k_cast_pad<<<cdiv_h(NDT * KDT / 4, 256), 256, 0, stream>>>(dtw, wb, ED, DTR, KDT, NDT);
    k_gemm_bf16<<<dim3(NDT / 128, NBS / 128), 256, 0, stream>>>(dbc_b, wb, delta_raw, nullptr, KDT, NDT, NDT);

    k_prepA<<<cdiv_h(NSTATE * ED, 256), 256, 0, stream>>>(al, A_t);
    k_scan2<<<dim3(cdiv_h(ED, 256), B_SZ), 256, 0, stream>>>(
        delta_raw, dbc, dtb, A_t, dp, xz, xc_f, xc_b);

    // out_proj: h[1536,1550] += xc_b @ opw_b^T
    k_cast_pad<<<cdiv_h(NOP * KE / 4, 256), 256, 0, stream>>>(opw, wb, D_MODEL, ED, KE, NOP);
    k_gemm_bf16<<<dim3(NOP / 128, NBS / 128), 256, 0, stream>>>(xc_b, wb, h, h, KE, D_MODEL, D_MODEL);
  }

  // final norm + lm head (bf16 MFMA)
  k_rmsnorm_bf16<<<NBS, 256, 0, stream>>>(h, normf_w, hn_b, D_MODEL, KD);
  k_cast_pad<<<cdiv_h(VOCAB * KD / 4, 256), 256, 0, stream>>>(lm_head_w, wb, VOCAB, D_MODEL, KD, VOCAB);
  k_gemm_bf16<<<dim3(1, NBS / 128), 256, 0, stream>>>(hn_b, wb, logits, nullptr, KD, VOCAB, VOCAB);

  k_stats<<<1, 1024, 0, stream>>>(logits, stats);
  k_sumw<<<1, 256, 0, stream>>>(emb_w, sumw);
  k_gemm_nt<<<dim3(cdiv_h(256, BN), cdiv_h(NBS, BM)), 256, 0, stream>>>(
      logits, emb_w, proj, nullptr, NBS, 256, VOCAB);
  k_final<<<cdiv_h(B_SZ * 5 * SEQ * 256, 256), 256, 0, stream>>>(
      proj, sumw, stats, bn_w, bn_b, emb_b, (float*)d_out);
}

// Round 4
// 672.306 us; speedup vs baseline: 6.1982x; 1.3758x over previous
//
#include <hip/hip_runtime.h>
#include <hip/hip_bf16.h>
#include <math.h>

#define B_SZ 512
#define SEQ 3
#define D_MODEL 1550
#define ED 3100
#define NSTATE 16
#define DTR 97
#define DBC_R 129   // DTR + 2*NSTATE
#define VOCAB 128
#define NBS (B_SZ*SEQ)       // 1536
#define EPSV 1e-5f

// padded dims
#define KD 1600     // D_MODEL -> 64*25
#define KE 3136     // ED -> 64*49
#define NIP 6272    // 2*ED=6200 -> 49*128
#define NXP 256     // 129 -> 2*128
#define NOP 1664    // 1550 -> 13*128
#define NDT 3200    // ED -> 25*128
#define KDT 128     // DTR -> 128
#define DBC_LD 256

static inline int cdiv_h(int a, int b){ return (a + b - 1) / b; }

__device__ __forceinline__ float silu_f(float x){ return x / (1.0f + expf(-x)); }

using bf16x8 = __attribute__((ext_vector_type(8))) short;
using f32x4  = __attribute__((ext_vector_type(4))) float;

__device__ __forceinline__ void gload16(const void* g, void* l){
  __builtin_amdgcn_global_load_lds(
      (const __attribute__((address_space(1))) unsigned int*)g,
      (__attribute__((address_space(3))) unsigned int*)l,
      16, 0, 0);
}

// ---------------- permute: x (B,S,F,C,E) -> h (B*S, C*F*E) with d=(c*F+f)*E+e
__global__ void k_permute(const float* __restrict__ x, float* __restrict__ h){
  int idx = blockIdx.x * 256 + threadIdx.x;
  if (idx >= NBS * D_MODEL) return;
  int d = idx % D_MODEL;
  int row = idx / D_MODEL;
  int e = d % 5;
  int f = (d / 5) % 5;
  int c = d / 25;
  h[idx] = x[(((size_t)row * 5 + f) * 62 + c) * 5 + e];
}

// ---------------- zero fill
__global__ void k_zero(float* __restrict__ p, int n){
  int i = blockIdx.x * 256 + threadIdx.x;
  if (i < n) p[i] = 0.f;
}

// ---------------- rmsnorm -> bf16 padded row
__global__ void k_rmsnorm_bf16(const float* __restrict__ in, const float* __restrict__ w,
                               __hip_bfloat16* __restrict__ out, int D, int Kp){
  int row = blockIdx.x;
  const float* xr = in + (size_t)row * D;
  float ss = 0.f;
  for (int i = threadIdx.x; i < D; i += blockDim.x){ float v = xr[i]; ss = fmaf(v, v, ss); }
  __shared__ float red[4];
  __shared__ float sscale;
  int lane = threadIdx.x & 63, wv = threadIdx.x >> 6;
  #pragma unroll
  for (int o = 32; o > 0; o >>= 1) ss += __shfl_down(ss, o, 64);
  if (lane == 0) red[wv] = ss;
  __syncthreads();
  if (threadIdx.x == 0){
    float t = red[0] + red[1] + red[2] + red[3];
    sscale = 1.0f / sqrtf(t / (float)D + EPSV);
  }
  __syncthreads();
  float sc = sscale;
  __hip_bfloat16* orow = out + (size_t)row * Kp;
  for (int i = threadIdx.x; i < Kp; i += blockDim.x){
    float v = (i < D) ? xr[i] * sc * w[i] : 0.f;
    orow[i] = __float2bfloat16(v);
  }
}

// ---------------- cast + pad weight: src fp32 [N][K] -> dst bf16 [Np][Kp]
__global__ void k_cast_pad(const float* __restrict__ src, __hip_bfloat16* __restrict__ dst,
                           int N, int K, int Kp, int Np){
  size_t i4 = ((size_t)blockIdx.x * 256 + threadIdx.x) * 4;
  if (i4 >= (size_t)Np * Kp) return;
  int row = (int)(i4 / Kp);
  int col = (int)(i4 % Kp);
  const float* srow = src + (size_t)row * K;
  #pragma unroll
  for (int j = 0; j < 4; j++){
    int c = col + j;
    float v = (row < N && c < K) ? srow[c] : 0.f;
    dst[i4 + j] = __float2bfloat16(v);
  }
}

// ---------------- cast dbc dt-cols -> bf16 [NBS][128]
__global__ void k_cast_dbc(const float* __restrict__ dbc, __hip_bfloat16* __restrict__ dst){
  int idx = blockIdx.x * 256 + threadIdx.x;
  if (idx >= NBS * KDT) return;
  int row = idx >> 7;
  int c = idx & 127;
  float v = (c < DTR) ? dbc[(size_t)row * DBC_LD + c] : 0.f;
  dst[idx] = __float2bfloat16(v);
}

// ---------------- cast logits fp32 -> bf16
__global__ void k_cast_l(const float* __restrict__ src, __hip_bfloat16* __restrict__ dst, int n){
  int i = blockIdx.x * 256 + threadIdx.x;
  if (i < n) dst[i] = __float2bfloat16(src[i]);
}

// ---------------- A_t[n][ch] = -exp(A_log[ch][n])
__global__ void k_prepA(const float* __restrict__ A_log, float* __restrict__ A_t){
  int idx = blockIdx.x * 256 + threadIdx.x;
  if (idx >= NSTATE * ED) return;
  int n = idx / ED;
  int ch = idx % ED;
  A_t[idx] = -expf(A_log[(size_t)ch * NSTATE + n]);
}

// ---------------- 2-phase double-buffered bf16 MFMA NT GEMM
// C[M,Nld] (+)= A[M,Kp] * B[Npad,Kp]^T over K chunk blockIdx.z.
// M mult of 128 (grid.y), Npad mult of 128 (grid.x). Kp mult of 32.
template<int SPLITS, bool ATOMIC, bool OUT_BF16>
__global__ __launch_bounds__(256)
void k_gemm2(const __hip_bfloat16* __restrict__ A, const __hip_bfloat16* __restrict__ B,
             void* Cv, int Kp, int Nld, int Nreal){
  __shared__ short Al[2][4096];   // [buf][128 rows x 32 k]
  __shared__ short Bl[2][4096];
  const int bm = blockIdx.y * 128, bn = blockIdx.x * 128;
  const int t = threadIdx.x;
  const int tt8 = t * 8;

  int kb = 0, ke = Kp;
  if (SPLITS > 1){
    int Kc = ((Kp / SPLITS + 31) / 32) * 32;
    kb = blockIdx.z * Kc;
    ke = min(kb + Kc, Kp);
    if (kb >= ke) return;
  }
  const int nt = (ke - kb) / 32;

  const short* Ab = (const short*)A;
  const short* Bb = (const short*)B;
  const short* ga0 = Ab + (size_t)(bm + (t >> 2)) * Kp + (t & 3) * 8;
  const short* ga1 = Ab + (size_t)(bm + 64 + (t >> 2)) * Kp + (t & 3) * 8;
  const short* gb0 = Bb + (size_t)(bn + (t >> 2)) * Kp + (t & 3) * 8;
  const short* gb1 = Bb + (size_t)(bn + 64 + (t >> 2)) * Kp + (t & 3) * 8;

  const int l = t & 63;
  const int wid = t >> 6;
  const int wr = wid >> 1, wc = wid & 1;
  const int fr = l & 15;
  const int ko = (l >> 4) * 8;

  f32x4 acc[4][4] = {};

#define STAGE(buf, kof) do{ \
    gload16(ga0 + (kof), &Al[buf][tt8]); \
    gload16(ga1 + (kof), &Al[buf][2048 + tt8]); \
    gload16(gb0 + (kof), &Bl[buf][tt8]); \
    gload16(gb1 + (kof), &Bl[buf][2048 + tt8]); }while(0)

  STAGE(0, kb);
  __syncthreads();
  int cur = 0;
  for (int it = 0; it < nt; ++it){
    if (it + 1 < nt) STAGE(cur ^ 1, kb + (it + 1) * 32);
    bf16x8 af[4], bfr[4];
    #pragma unroll
    for (int m = 0; m < 4; m++)
      af[m] = *(const bf16x8*)&Al[cur][(wr * 64 + m * 16 + fr) * 32 + ko];
    #pragma unroll
    for (int n = 0; n < 4; n++)
      bfr[n] = *(const bf16x8*)&Bl[cur][(wc * 64 + n * 16 + fr) * 32 + ko];
    #pragma unroll
    for (int m = 0; m < 4; m++)
      #pragma unroll
      for (int n = 0; n < 4; n++)
        acc[m][n] = __builtin_amdgcn_mfma_f32_16x16x32_bf16(af[m], bfr[n], acc[m][n], 0, 0, 0);
    if (it + 1 < nt){ __syncthreads(); cur ^= 1; }
  }
#undef STAGE

  float* Cf = (float*)Cv;
  __hip_bfloat16* Cb = (__hip_bfloat16*)Cv;
  const int r0 = (l >> 4) * 4;
  #pragma unroll
  for (int m = 0; m < 4; m++){
    #pragma unroll
    for (int n = 0; n < 4; n++){
      int col = bn + wc * 64 + n * 16 + fr;
      if (col < Nreal){
        size_t base = (size_t)(bm + wr * 64 + m * 16 + r0) * Nld + col;
        #pragma unroll
        for (int j = 0; j < 4; j++){
          float v = acc[m][n][j];
          size_t o = base + (size_t)j * Nld;
          if (OUT_BF16)      Cb[o] = __float2bfloat16(v);
          else if (ATOMIC)   atomicAdd(&Cf[o], v);
          else               Cf[o] = v;
        }
      }
    }
  }
}

// ---------------- causal depthwise conv (S=3, k=4) + silu (xz is bf16, stride NIP)
__global__ void k_conv_silu(const __hip_bfloat16* __restrict__ xz, const float* __restrict__ cw,
                            const float* __restrict__ cb, float* __restrict__ xc_f,
                            __hip_bfloat16* __restrict__ xc_b){
  int idx = blockIdx.x * 256 + threadIdx.x;
  if (idx >= B_SZ * KE) return;
  int ch = idx % KE;
  int b  = idx / KE;
  size_t ob = (size_t)b * SEQ * KE + ch;
  if (ch >= ED){
    __hip_bfloat16 z = __float2bfloat16(0.f);
    xc_b[ob] = z; xc_b[ob + KE] = z; xc_b[ob + 2 * KE] = z;
    return;
  }
  const __hip_bfloat16* base = xz + (size_t)b * SEQ * NIP + ch;
  float x0 = __bfloat162float(base[0]);
  float x1 = __bfloat162float(base[NIP]);
  float x2 = __bfloat162float(base[2 * NIP]);
  const float* w = cw + (size_t)ch * 4;
  float w1 = w[1], w2 = w[2], w3 = w[3];
  float bb = cb[ch];
  float s0 = silu_f(fmaf(w3, x0, bb));
  float s1 = silu_f(fmaf(w2, x0, fmaf(w3, x1, bb)));
  float s2 = silu_f(fmaf(w1, x0, fmaf(w2, x1, fmaf(w3, x2, bb))));
  size_t of = (size_t)b * SEQ * ED + ch;
  xc_f[of]          = s0;
  xc_f[of + ED]     = s1;
  xc_f[of + 2 * ED] = s2;
  xc_b[ob]          = __float2bfloat16(s0);
  xc_b[ob + KE]     = __float2bfloat16(s1);
  xc_b[ob + 2 * KE] = __float2bfloat16(s2);
}

// ---------------- lean scan: softplus(delta_b+bias) + SSM + D skip + z gate -> bf16
__global__ __launch_bounds__(256)
void k_scan2(const __hip_bfloat16* __restrict__ delta_b, const float* __restrict__ dbc,
             const float* __restrict__ dtb, const float* __restrict__ A_t,
             const float* __restrict__ Dp, const __hip_bfloat16* __restrict__ xz,
             const float* __restrict__ xc_f, __hip_bfloat16* __restrict__ xc_b){
  __shared__ float sB[SEQ][NSTATE], sC[SEQ][NSTATE];
  int b = blockIdx.y;
  if (threadIdx.x < SEQ * 2 * NSTATE){
    int t = threadIdx.x / (2 * NSTATE), r = threadIdx.x % (2 * NSTATE);
    float v = dbc[(size_t)(b * SEQ + t) * DBC_LD + DTR + r];
    if (r < NSTATE) sB[t][r] = v; else sC[t][r - NSTATE] = v;
  }
  __syncthreads();
  int ch = blockIdx.x * 256 + threadIdx.x;
  if (ch >= ED) return;

  float bias = dtb[ch];
  float dlt[SEQ];
  #pragma unroll
  for (int t = 0; t < SEQ; t++){
    float acc = __bfloat162float(delta_b[(size_t)(b * SEQ + t) * NDT + ch]) + bias;
    dlt[t] = (acc > 20.f) ? acc : log1pf(expf(acc));
  }

  size_t of = (size_t)b * SEQ * ED + ch;
  float xcv[SEQ] = { xc_f[of], xc_f[of + ED], xc_f[of + 2 * ED] };
  float y[SEQ] = {0.f, 0.f, 0.f};
  #pragma unroll
  for (int n = 0; n < NSTATE; n++){
    float Av = A_t[(size_t)n * ED + ch];
    float hs = 0.f;
    #pragma unroll
    for (int t = 0; t < SEQ; t++){
      float dA = expf(dlt[t] * Av);
      hs = fmaf(dA, hs, dlt[t] * sB[t][n] * xcv[t]);
      y[t] = fmaf(hs, sC[t][n], y[t]);
    }
  }
  float dp = Dp[ch];
  const __hip_bfloat16* zbase = xz + (size_t)b * SEQ * NIP + ED + ch;
  size_t ob = (size_t)b * SEQ * KE + ch;
  #pragma unroll
  for (int t = 0; t < SEQ; t++){
    float z = __bfloat162float(zbase[(size_t)t * NIP]);
    float yy = fmaf(dp, xcv[t], y[t]);
    xc_b[ob + (size_t)t * KE] = __float2bfloat16(yy * silu_f(z));
  }
}

// ---------------- logits stats (single block)
__global__ void k_stats(const float* __restrict__ logits, float* __restrict__ stats){
  float s = 0.f, ss = 0.f;
  for (int i = threadIdx.x; i < NBS * VOCAB; i += 1024){
    float v = logits[i]; s += v; ss = fmaf(v, v, ss);
  }
  __shared__ float rs[16], rss[16];
  #pragma unroll
  for (int o = 32; o > 0; o >>= 1){ s += __shfl_down(s, o, 64); ss += __shfl_down(ss, o, 64); }
  int lane = threadIdx.x & 63, wv = threadIdx.x >> 6;
  if (lane == 0){ rs[wv] = s; rss[wv] = ss; }
  __syncthreads();
  if (threadIdx.x == 0){
    float S1 = 0.f, S2 = 0.f;
    for (int i = 0; i < 16; i++){ S1 += rs[i]; S2 += rss[i]; }
    const float invN = 1.0f / (float)(NBS * VOCAB);
    float mean = S1 * invN;
    float var = S2 * invN - mean * mean;
    stats[0] = mean;
    stats[1] = 1.0f / sqrtf(var + EPSV);
  }
}

__global__ void k_sumw(const float* __restrict__ emb_w, float* __restrict__ sumw){
  int o = threadIdx.x;
  const float* r = emb_w + (size_t)o * VOCAB;
  float s = 0.f;
  for (int v = 0; v < VOCAB; v++) s += r[v];
  sumw[o] = s;
}

__global__ void k_final(const float* __restrict__ proj, const float* __restrict__ sumw,
                        const float* __restrict__ stats, const float* __restrict__ bnw,
                        const float* __restrict__ bnb, const float* __restrict__ embb,
                        float* __restrict__ out){
  size_t idx = (size_t)blockIdx.x * 256 + threadIdx.x;
  if (idx >= (size_t)B_SZ * 5 * SEQ * 256) return;
  int o = idx & 255;
  size_t r = idx >> 8;
  int s = (int)(r % SEQ);
  size_t bf = r / SEQ;
  int f = (int)(bf % 5);
  size_t b = bf / 5;
  float mean = stats[0], rstd = stats[1];
  float p = proj[((b * SEQ) + s) * 256 + o];
  float sw = sumw[o];
  out[idx] = bnw[f] * rstd * (p - mean * sw) + bnb[f] * sw + embb[o];
}

extern "C" void kernel_launch(void* const* d_in, const int* in_sizes, int n_in,
                              void* d_out, int out_size, void* d_ws, size_t ws_size,
                              hipStream_t stream) {
  const float* x          = (const float*)d_in[0];
  const float* in_proj_w  = (const float*)d_in[1];
  const float* conv_w     = (const float*)d_in[2];
  const float* conv_b     = (const float*)d_in[3];
  const float* x_proj_w   = (const float*)d_in[4];
  const float* dt_proj_w  = (const float*)d_in[5];
  const float* dt_proj_b  = (const float*)d_in[6];
  const float* A_log      = (const float*)d_in[7];
  const float* D_param    = (const float*)d_in[8];
  const float* out_proj_w = (const float*)d_in[9];
  const float* norm_w     = (const float*)d_in[10];
  const float* normf_w    = (const float*)d_in[11];
  const float* lm_head_w  = (const float*)d_in[12];
  const float* bn_w       = (const float*)d_in[13];
  const float* bn_b       = (const float*)d_in[14];
  const float* emb_w      = (const float*)d_in[15];
  const float* emb_b      = (const float*)d_in[16];

  float* ws = (float*)d_ws;
  float* h      = ws;                                   // NBS*D_MODEL
  float* xc_f   = h      + (size_t)NBS * D_MODEL;       // NBS*ED
  float* dbc    = xc_f   + (size_t)NBS * ED;            // NBS*DBC_LD
  float* logits = dbc    + (size_t)NBS * DBC_LD;        // NBS*VOCAB
  float* proj   = logits + (size_t)NBS * VOCAB;         // NBS*256
  float* sumw   = proj   + (size_t)NBS * 256;           // 256
  float* stats  = sumw   + 256;                         // 4
  float* A_t    = stats  + 4;                           // NSTATE*ED
  __hip_bfloat16* xz_b   = (__hip_bfloat16*)(A_t + (size_t)NSTATE * ED); // NBS*NIP
  __hip_bfloat16* hn_b   = xz_b   + (size_t)NBS * NIP;  // NBS*KD
  __hip_bfloat16* xc_b   = hn_b   + (size_t)NBS * KD;   // NBS*KE
  __hip_bfloat16* dbc_b  = xc_b   + (size_t)NBS * KE;   // NBS*KDT
  __hip_bfloat16* dlt_b  = dbc_b  + (size_t)NBS * KDT;  // NBS*NDT
  __hip_bfloat16* lgt_b  = dlt_b  + (size_t)NBS * NDT;  // NBS*VOCAB
  __hip_bfloat16* wb     = lgt_b  + (size_t)NBS * VOCAB;// NIP*KD (max weight)
  size_t need = (size_t)((char*)(wb + (size_t)NIP * KD) - (char*)ws);
  if (ws_size < need) return;

  k_permute<<<cdiv_h(NBS * D_MODEL, 256), 256, 0, stream>>>(x, h);

  for (int l = 0; l < 2; l++){
    const float* ipw = in_proj_w  + (size_t)l * 2 * ED * D_MODEL;
    const float* cw  = conv_w     + (size_t)l * ED * 4;
    const float* cb  = conv_b     + (size_t)l * ED;
    const float* xpw = x_proj_w   + (size_t)l * DBC_R * ED;
    const float* dtw = dt_proj_w  + (size_t)l * ED * DTR;
    const float* dtb = dt_proj_b  + (size_t)l * ED;
    const float* al  = A_log      + (size_t)l * ED * NSTATE;
    const float* dp  = D_param    + (size_t)l * ED;
    const float* opw = out_proj_w + (size_t)l * D_MODEL * ED;
    const float* nw  = norm_w     + (size_t)l * D_MODEL;

    k_rmsnorm_bf16<<<NBS, 256, 0, stream>>>(h, nw, hn_b, D_MODEL, KD);

    // in_proj: xz_b[1536,6272](bf16) = hn_b @ ipw_b^T
    k_cast_pad<<<cdiv_h(NIP * KD / 4, 256), 256, 0, stream>>>(ipw, wb, 2 * ED, D_MODEL, KD, NIP);
    k_gemm2<1, false, true><<<dim3(NIP / 128, NBS / 128, 1), 256, 0, stream>>>(
        hn_b, wb, xz_b, KD, NIP, NIP);

    k_conv_silu<<<cdiv_h(B_SZ * KE, 256), 256, 0, stream>>>(xz_b, cw, cb, xc_f, xc_b);

    // x_proj (split-K 8, atomic): dbc[1536,256] += xc_b @ xpw_b^T
    k_cast_pad<<<cdiv_h(NXP * KE / 4, 256), 256, 0, stream>>>(xpw, wb, DBC_R, ED, KE, NXP);
    k_zero<<<cdiv_h(NBS * DBC_LD, 256), 256, 0, stream>>>(dbc, NBS * DBC_LD);
    k_gemm2<8, true, false><<<dim3(NXP / 128, NBS / 128, 8), 256, 0, stream>>>(
        xc_b, wb, dbc, KE, DBC_LD, DBC_LD);

    // dt_proj: dlt_b[1536,3200](bf16) = dbc_b[1536,128] @ dtw_b[3200,128]^T
    k_cast_dbc<<<cdiv_h(NBS * KDT, 256), 256, 0, stream>>>(dbc, dbc_b);
    k_cast_pad<<<cdiv_h(NDT * KDT / 4, 256), 256, 0, stream>>>(dtw, wb, ED, DTR, KDT, NDT);
    k_gemm2<1, false, true><<<dim3(NDT / 128, NBS / 128, 1), 256, 0, stream>>>(
        dbc_b, wb, dlt_b, KDT, NDT, NDT);

    k_prepA<<<cdiv_h(NSTATE * ED, 256), 256, 0, stream>>>(al, A_t);
    k_scan2<<<dim3(cdiv_h(ED, 256), B_SZ), 256, 0, stream>>>(
        dlt_b, dbc, dtb, A_t, dp, xz_b, xc_f, xc_b);

    // out_proj (split-K 2, atomic, residual in place): h += xc_b @ opw_b^T
    k_cast_pad<<<cdiv_h(NOP * KE / 4, 256), 256, 0, stream>>>(opw, wb, D_MODEL, ED, KE, NOP);
    k_gemm2<2, true, false><<<dim3(NOP / 128, NBS / 128, 2), 256, 0, stream>>>(
        xc_b, wb, h, KE, D_MODEL, D_MODEL);
  }

  // final norm + lm head (split-K 4, atomic)
  k_rmsnorm_bf16<<<NBS, 256, 0, stream>>>(h, normf_w, hn_b, D_MODEL, KD);
  k_cast_pad<<<cdiv_h(VOCAB * KD / 4, 256), 256, 0, stream>>>(lm_head_w, wb, VOCAB, D_MODEL, KD, VOCAB);
  k_zero<<<cdiv_h(NBS * VOCAB, 256), 256, 0, stream>>>(logits, NBS * VOCAB);
  k_gemm2<4, true, false><<<dim3(1, NBS / 128, 4), 256, 0, stream>>>(
      hn_b, wb, logits, KD, VOCAB, VOCAB);

  k_stats<<<1, 1024, 0, stream>>>(logits, stats);
  k_sumw<<<1, 256, 0, stream>>>(emb_w, sumw);

  // emb projection via MFMA: proj[1536,256] = lgt_b @ emb_b16^T
  k_cast_l<<<cdiv_h(NBS * VOCAB, 256), 256, 0, stream>>>(logits, lgt_b, NBS * VOCAB);
  k_cast_pad<<<cdiv_h(256 * VOCAB / 4, 256), 256, 0, stream>>>(emb_w, wb, 256, VOCAB, VOCAB, 256);
  k_gemm2<1, false, false><<<dim3(2, NBS / 128, 1), 256, 0, stream>>>(
      lgt_b, wb, proj, VOCAB, 256, 256);

  k_final<<<cdiv_h(B_SZ * 5 * SEQ * 256, 256), 256, 0, stream>>>(
      proj, sumw, stats, bn_w, bn_b, emb_b, (float*)d_out);
}

// Round 5
// 550.697 us; speedup vs baseline: 7.5670x; 1.2208x over previous
//
#include <hip/hip_runtime.h>
#include <hip/hip_bf16.h>
#include <math.h>

#define B_SZ 512
#define SEQ 3
#define D_MODEL 1550
#define ED 3100
#define NSTATE 16
#define DTR 97
#define DBC_R 129   // DTR + 2*NSTATE
#define VOCAB 128
#define NBS (B_SZ*SEQ)       // 1536
#define EPSV 1e-5f

// padded dims
#define KD 1600     // D_MODEL -> 64*25
#define KE 3136     // ED -> 64*49
#define NIP 6272    // 2*ED=6200 -> 49*128
#define NXP 256     // 129 -> 2*128
#define NOP 1664    // 1550 -> 13*128
#define NDT 3200    // ED -> 25*128
#define KDT 128     // DTR -> 128
#define DBC_LD 256

// prep job sizes (quads of 4 elems unless noted)
#define QIP 2508800   // NIP*KD/4
#define QXP 200704    // NXP*KE/4
#define QDT 102400    // NDT*KDT/4
#define QOP 1304576   // NOP*KE/4
#define AEL 49600     // NSTATE*ED scalars
#define QDB 98304     // NBS*DBC_LD/4
#define QLM 51200     // VOCAB*KD/4
#define QLG 49152     // NBS*VOCAB/4
#define TEL 32768     // VOCAB*256 scalars (emb transpose)
#define PREP_N0 4397762   // QIP+QXP+QDT+QOP+AEL+QDB+QLM+QLG+TEL+258
#define PREP_N1 4264384   // QIP+QXP+QDT+QOP+AEL+QDB

static inline int cdiv_h(int a, int b){ return (a + b - 1) / b; }

__device__ __forceinline__ float silu_f(float x){ return x / (1.0f + expf(-x)); }

using bf16x8 = __attribute__((ext_vector_type(8))) short;
using f32x4  = __attribute__((ext_vector_type(4))) float;

__device__ __forceinline__ void gload16(const void* g, void* l){
  __builtin_amdgcn_global_load_lds(
      (const __attribute__((address_space(1))) unsigned int*)g,
      (__attribute__((address_space(3))) unsigned int*)l,
      16, 0, 0);
}

// ---------------- permute: x (B,S,F,C,E) -> h (B*S, C*F*E) with d=(c*F+f)*E+e
__global__ void k_permute(const float* __restrict__ x, float* __restrict__ h){
  int idx = blockIdx.x * 256 + threadIdx.x;
  if (idx >= NBS * D_MODEL) return;
  int d = idx % D_MODEL;
  int row = idx / D_MODEL;
  int e = d % 5;
  int f = (d / 5) % 5;
  int c = d / 25;
  h[idx] = x[(((size_t)row * 5 + f) * 62 + c) * 5 + e];
}

// ---------------- cast+pad quad helper
__device__ __forceinline__ void cast4(const float* __restrict__ src,
                                      __hip_bfloat16* __restrict__ dst,
                                      int q, int N, int K, int Kp){
  int i4 = q * 4;
  int row = i4 / Kp;
  int col = i4 % Kp;
  const float* srow = src + (size_t)row * K;
  #pragma unroll
  for (int j = 0; j < 4; j++){
    int c = col + j;
    float v = (row < N && c < K) ? srow[c] : 0.f;
    dst[i4 + j] = __float2bfloat16(v);
  }
}

// ---------------- one-shot per-layer prep: weight casts + A_t + zero fills (+ layer0 extras)
__global__ __launch_bounds__(256)
void k_prep(const float* __restrict__ ipw, const float* __restrict__ xpw,
            const float* __restrict__ dtw, const float* __restrict__ opw,
            const float* __restrict__ alog,
            const float* __restrict__ lmw, const float* __restrict__ embw,
            __hip_bfloat16* __restrict__ ipb, __hip_bfloat16* __restrict__ xpb,
            __hip_bfloat16* __restrict__ dtwb, __hip_bfloat16* __restrict__ opb,
            float* __restrict__ A_t, float* __restrict__ dbc,
            __hip_bfloat16* __restrict__ lmb, float* __restrict__ logits,
            float* __restrict__ emb_t, float* __restrict__ sumw,
            float* __restrict__ stats, int l0){
  int idx = blockIdx.x * 256 + threadIdx.x;
  if (idx < QIP){ cast4(ipw, ipb, idx, 2 * ED, D_MODEL, KD); return; } idx -= QIP;
  if (idx < QXP){ cast4(xpw, xpb, idx, DBC_R, ED, KE); return; } idx -= QXP;
  if (idx < QDT){ cast4(dtw, dtwb, idx, ED, DTR, KDT); return; } idx -= QDT;
  if (idx < QOP){ cast4(opw, opb, idx, D_MODEL, ED, KE); return; } idx -= QOP;
  if (idx < AEL){
    int n = idx / ED, ch = idx % ED;
    A_t[idx] = -expf(alog[(size_t)ch * NSTATE + n]);
    return;
  } idx -= AEL;
  if (idx < QDB){
    int i4 = idx * 4;
    dbc[i4] = 0.f; dbc[i4+1] = 0.f; dbc[i4+2] = 0.f; dbc[i4+3] = 0.f;
    return;
  } idx -= QDB;
  if (!l0) return;
  if (idx < QLM){ cast4(lmw, lmb, idx, VOCAB, D_MODEL, KD); return; } idx -= QLM;
  if (idx < QLG){
    int i4 = idx * 4;
    logits[i4] = 0.f; logits[i4+1] = 0.f; logits[i4+2] = 0.f; logits[i4+3] = 0.f;
    return;
  } idx -= QLG;
  if (idx < TEL){
    int v = idx >> 8, o = idx & 255;
    emb_t[idx] = embw[(size_t)o * VOCAB + v];
    return;
  } idx -= TEL;
  if (idx < 256){
    const float* r = embw + (size_t)idx * VOCAB;
    float s = 0.f;
    for (int v = 0; v < VOCAB; v++) s += r[v];
    sumw[idx] = s;
    return;
  } idx -= 256;
  if (idx < 2) stats[idx] = 0.f;
}

// ---------------- rmsnorm -> bf16 padded row
__global__ void k_rmsnorm_bf16(const float* __restrict__ in, const float* __restrict__ w,
                               __hip_bfloat16* __restrict__ out, int D, int Kp){
  int row = blockIdx.x;
  const float* xr = in + (size_t)row * D;
  float ss = 0.f;
  for (int i = threadIdx.x; i < D; i += blockDim.x){ float v = xr[i]; ss = fmaf(v, v, ss); }
  __shared__ float red[4];
  __shared__ float sscale;
  int lane = threadIdx.x & 63, wv = threadIdx.x >> 6;
  #pragma unroll
  for (int o = 32; o > 0; o >>= 1) ss += __shfl_down(ss, o, 64);
  if (lane == 0) red[wv] = ss;
  __syncthreads();
  if (threadIdx.x == 0){
    float t = red[0] + red[1] + red[2] + red[3];
    sscale = 1.0f / sqrtf(t / (float)D + EPSV);
  }
  __syncthreads();
  float sc = sscale;
  __hip_bfloat16* orow = out + (size_t)row * Kp;
  for (int i = threadIdx.x; i < Kp; i += blockDim.x){
    float v = (i < D) ? xr[i] * sc * w[i] : 0.f;
    orow[i] = __float2bfloat16(v);
  }
}

// ---------------- cast dbc dt-cols -> bf16 [NBS][128]
__global__ void k_cast_dbc(const float* __restrict__ dbc, __hip_bfloat16* __restrict__ dst){
  int idx = blockIdx.x * 256 + threadIdx.x;
  if (idx >= NBS * KDT) return;
  int row = idx >> 7;
  int c = idx & 127;
  float v = (c < DTR) ? dbc[(size_t)row * DBC_LD + c] : 0.f;
  dst[idx] = __float2bfloat16(v);
}

// ---------------- 2-phase double-buffered bf16 MFMA NT GEMM + XCD-chunked swizzle
// C[M,Nld] (+)= A[M,Kp] * B[Npad,Kp]^T over K chunk blockIdx.z.
template<int SPLITS, bool ATOMIC, bool OUT_BF16>
__global__ __launch_bounds__(256)
void k_gemm2(const __hip_bfloat16* __restrict__ A, const __hip_bfloat16* __restrict__ B,
             void* Cv, int Kp, int Nld, int Nreal){
  __shared__ short Al[2][4096];   // [buf][128 rows x 32 k]
  __shared__ short Bl[2][4096];
  // XCD-aware bijective swizzle (m204), column-major decode so each XCD
  // chunk walks rows within few columns -> B panel stays L2-resident.
  const int gx = gridDim.x, gy = gridDim.y;
  const int nwg = gx * gy;
  const int wg = blockIdx.y * gx + blockIdx.x;
  const int q = nwg >> 3, r = nwg & 7;
  const int xcd = wg & 7, off = wg >> 3;
  const int nid = (xcd < r ? xcd * (q + 1) : r * (q + 1) + (xcd - r) * q) + off;
  const int bm = (nid % gy) * 128;
  const int bn = (nid / gy) * 128;

  const int t = threadIdx.x;
  const int tt8 = t * 8;

  int kb = 0, ke = Kp;
  if (SPLITS > 1){
    int Kc = ((Kp / SPLITS + 31) / 32) * 32;
    kb = blockIdx.z * Kc;
    ke = min(kb + Kc, Kp);
    if (kb >= ke) return;
  }
  const int nt = (ke - kb) / 32;

  const short* Ab = (const short*)A;
  const short* Bb = (const short*)B;
  const short* ga0 = Ab + (size_t)(bm + (t >> 2)) * Kp + (t & 3) * 8;
  const short* ga1 = Ab + (size_t)(bm + 64 + (t >> 2)) * Kp + (t & 3) * 8;
  const short* gb0 = Bb + (size_t)(bn + (t >> 2)) * Kp + (t & 3) * 8;
  const short* gb1 = Bb + (size_t)(bn + 64 + (t >> 2)) * Kp + (t & 3) * 8;

  const int l = t & 63;
  const int wid = t >> 6;
  const int wr = wid >> 1, wc = wid & 1;
  const int fr = l & 15;
  const int ko = (l >> 4) * 8;

  f32x4 acc[4][4] = {};

#define STAGE(buf, kof) do{ \
    gload16(ga0 + (kof), &Al[buf][tt8]); \
    gload16(ga1 + (kof), &Al[buf][2048 + tt8]); \
    gload16(gb0 + (kof), &Bl[buf][tt8]); \
    gload16(gb1 + (kof), &Bl[buf][2048 + tt8]); }while(0)

  STAGE(0, kb);
  __syncthreads();
  int cur = 0;
  for (int it = 0; it < nt; ++it){
    if (it + 1 < nt) STAGE(cur ^ 1, kb + (it + 1) * 32);
    bf16x8 af[4], bfr[4];
    #pragma unroll
    for (int m = 0; m < 4; m++)
      af[m] = *(const bf16x8*)&Al[cur][(wr * 64 + m * 16 + fr) * 32 + ko];
    #pragma unroll
    for (int n = 0; n < 4; n++)
      bfr[n] = *(const bf16x8*)&Bl[cur][(wc * 64 + n * 16 + fr) * 32 + ko];
    #pragma unroll
    for (int m = 0; m < 4; m++)
      #pragma unroll
      for (int n = 0; n < 4; n++)
        acc[m][n] = __builtin_amdgcn_mfma_f32_16x16x32_bf16(af[m], bfr[n], acc[m][n], 0, 0, 0);
    if (it + 1 < nt){ __syncthreads(); cur ^= 1; }
  }
#undef STAGE

  float* Cf = (float*)Cv;
  __hip_bfloat16* Cb = (__hip_bfloat16*)Cv;
  const int r0 = (l >> 4) * 4;
  #pragma unroll
  for (int m = 0; m < 4; m++){
    #pragma unroll
    for (int n = 0; n < 4; n++){
      int col = bn + wc * 64 + n * 16 + fr;
      if (col < Nreal){
        size_t base = (size_t)(bm + wr * 64 + m * 16 + r0) * Nld + col;
        #pragma unroll
        for (int j = 0; j < 4; j++){
          float v = acc[m][n][j];
          size_t o = base + (size_t)j * Nld;
          if (OUT_BF16)      Cb[o] = __float2bfloat16(v);
          else if (ATOMIC)   atomicAdd(&Cf[o], v);
          else               Cf[o] = v;
        }
      }
    }
  }
}

// ---------------- causal depthwise conv (S=3, k=4) + silu (xz is bf16, stride NIP)
__global__ void k_conv_silu(const __hip_bfloat16* __restrict__ xz, const float* __restrict__ cw,
                            const float* __restrict__ cb, float* __restrict__ xc_f,
                            __hip_bfloat16* __restrict__ xc_b){
  int idx = blockIdx.x * 256 + threadIdx.x;
  if (idx >= B_SZ * KE) return;
  int ch = idx % KE;
  int b  = idx / KE;
  size_t ob = (size_t)b * SEQ * KE + ch;
  if (ch >= ED){
    __hip_bfloat16 z = __float2bfloat16(0.f);
    xc_b[ob] = z; xc_b[ob + KE] = z; xc_b[ob + 2 * KE] = z;
    return;
  }
  const __hip_bfloat16* base = xz + (size_t)b * SEQ * NIP + ch;
  float x0 = __bfloat162float(base[0]);
  float x1 = __bfloat162float(base[NIP]);
  float x2 = __bfloat162float(base[2 * NIP]);
  const float* w = cw + (size_t)ch * 4;
  float w1 = w[1], w2 = w[2], w3 = w[3];
  float bb = cb[ch];
  float s0 = silu_f(fmaf(w3, x0, bb));
  float s1 = silu_f(fmaf(w2, x0, fmaf(w3, x1, bb)));
  float s2 = silu_f(fmaf(w1, x0, fmaf(w2, x1, fmaf(w3, x2, bb))));
  size_t of = (size_t)b * SEQ * ED + ch;
  xc_f[of]          = s0;
  xc_f[of + ED]     = s1;
  xc_f[of + 2 * ED] = s2;
  xc_b[ob]          = __float2bfloat16(s0);
  xc_b[ob + KE]     = __float2bfloat16(s1);
  xc_b[ob + 2 * KE] = __float2bfloat16(s2);
}

// ---------------- lean scan: softplus(delta_b+bias) + SSM + D skip + z gate -> bf16
__global__ __launch_bounds__(256)
void k_scan2(const __hip_bfloat16* __restrict__ delta_b, const float* __restrict__ dbc,
             const float* __restrict__ dtb, const float* __restrict__ A_t,
             const float* __restrict__ Dp, const __hip_bfloat16* __restrict__ xz,
             const float* __restrict__ xc_f, __hip_bfloat16* __restrict__ xc_b){
  __shared__ float sB[SEQ][NSTATE], sC[SEQ][NSTATE];
  int b = blockIdx.y;
  if (threadIdx.x < SEQ * 2 * NSTATE){
    int t = threadIdx.x / (2 * NSTATE), r = threadIdx.x % (2 * NSTATE);
    float v = dbc[(size_t)(b * SEQ + t) * DBC_LD + DTR + r];
    if (r < NSTATE) sB[t][r] = v; else sC[t][r - NSTATE] = v;
  }
  __syncthreads();
  int ch = blockIdx.x * 256 + threadIdx.x;
  if (ch >= ED) return;

  float bias = dtb[ch];
  float dlt[SEQ];
  #pragma unroll
  for (int t = 0; t < SEQ; t++){
    float acc = __bfloat162float(delta_b[(size_t)(b * SEQ + t) * NDT + ch]) + bias;
    dlt[t] = (acc > 20.f) ? acc : log1pf(expf(acc));
  }

  size_t of = (size_t)b * SEQ * ED + ch;
  float xcv[SEQ] = { xc_f[of], xc_f[of + ED], xc_f[of + 2 * ED] };
  float y[SEQ] = {0.f, 0.f, 0.f};
  #pragma unroll
  for (int n = 0; n < NSTATE; n++){
    float Av = A_t[(size_t)n * ED + ch];
    float hs = 0.f;
    #pragma unroll
    for (int t = 0; t < SEQ; t++){
      float dA = expf(dlt[t] * Av);
      hs = fmaf(dA, hs, dlt[t] * sB[t][n] * xcv[t]);
      y[t] = fmaf(hs, sC[t][n], y[t]);
    }
  }
  float dp = Dp[ch];
  const __hip_bfloat16* zbase = xz + (size_t)b * SEQ * NIP + ED + ch;
  size_t ob = (size_t)b * SEQ * KE + ch;
  #pragma unroll
  for (int t = 0; t < SEQ; t++){
    float z = __bfloat162float(zbase[(size_t)t * NIP]);
    float yy = fmaf(dp, xcv[t], y[t]);
    xc_b[ob + (size_t)t * KE] = __float2bfloat16(yy * silu_f(z));
  }
}

// ---------------- logits stats: grid partial reduce + atomics into stats[0..1]
__global__ __launch_bounds__(256)
void k_stats_part(const float* __restrict__ logits, float* __restrict__ stats){
  float s = 0.f, ss = 0.f;
  for (int i = blockIdx.x * 256 + threadIdx.x; i < NBS * VOCAB; i += gridDim.x * 256){
    float v = logits[i]; s += v; ss = fmaf(v, v, ss);
  }
  #pragma unroll
  for (int o = 32; o > 0; o >>= 1){ s += __shfl_down(s, o, 64); ss += __shfl_down(ss, o, 64); }
  __shared__ float rs[4], rss[4];
  int lane = threadIdx.x & 63, wv = threadIdx.x >> 6;
  if (lane == 0){ rs[wv] = s; rss[wv] = ss; }
  __syncthreads();
  if (threadIdx.x == 0){
    atomicAdd(&stats[0], rs[0] + rs[1] + rs[2] + rs[3]);
    atomicAdd(&stats[1], rss[0] + rss[1] + rss[2] + rss[3]);
  }
}

// ---------------- fused: proj = logits @ emb^T, BN normalize, write out[b,f,s,o]
__global__ __launch_bounds__(256)
void k_projfinal(const float* __restrict__ logits, const float* __restrict__ emb_t,
                 const float* __restrict__ sumw, const float* __restrict__ stats,
                 const float* __restrict__ bnw, const float* __restrict__ bnb,
                 const float* __restrict__ embb, float* __restrict__ out){
  __shared__ float row[VOCAB];
  int r = blockIdx.x;            // b*SEQ + s
  int o = threadIdx.x;           // 0..255
  if (o < VOCAB) row[o] = logits[(size_t)r * VOCAB + o];
  __syncthreads();
  float p = 0.f;
  #pragma unroll 8
  for (int v = 0; v < VOCAB; v++) p = fmaf(row[v], emb_t[v * 256 + o], p);
  const float invN = 1.0f / (float)(NBS * VOCAB);
  float mean = stats[0] * invN;
  float var  = stats[1] * invN - mean * mean;
  float rstd = rsqrtf(var + EPSV);
  int b = r / SEQ, s = r % SEQ;
  float sw = sumw[o];
  float base = rstd * (p - mean * sw);
  float eb = embb[o];
  #pragma unroll
  for (int f = 0; f < 5; f++){
    out[(((size_t)(b * 5 + f)) * SEQ + s) * 256 + o] = bnw[f] * base + bnb[f] * sw + eb;
  }
}

extern "C" void kernel_launch(void* const* d_in, const int* in_sizes, int n_in,
                              void* d_out, int out_size, void* d_ws, size_t ws_size,
                              hipStream_t stream) {
  const float* x          = (const float*)d_in[0];
  const float* in_proj_w  = (const float*)d_in[1];
  const float* conv_w     = (const float*)d_in[2];
  const float* conv_b     = (const float*)d_in[3];
  const float* x_proj_w   = (const float*)d_in[4];
  const float* dt_proj_w  = (const float*)d_in[5];
  const float* dt_proj_b  = (const float*)d_in[6];
  const float* A_log      = (const float*)d_in[7];
  const float* D_param    = (const float*)d_in[8];
  const float* out_proj_w = (const float*)d_in[9];
  const float* norm_w     = (const float*)d_in[10];
  const float* normf_w    = (const float*)d_in[11];
  const float* lm_head_w  = (const float*)d_in[12];
  const float* bn_w       = (const float*)d_in[13];
  const float* bn_b       = (const float*)d_in[14];
  const float* emb_w      = (const float*)d_in[15];
  const float* emb_b      = (const float*)d_in[16];

  float* ws = (float*)d_ws;
  float* h      = ws;                                   // NBS*D_MODEL
  float* xc_f   = h      + (size_t)NBS * D_MODEL;       // NBS*ED
  float* dbc    = xc_f   + (size_t)NBS * ED;            // NBS*DBC_LD
  float* logits = dbc    + (size_t)NBS * DBC_LD;        // NBS*VOCAB
  float* sumw   = logits + (size_t)NBS * VOCAB;         // 256
  float* stats  = sumw   + 256;                         // 2
  float* A_t    = stats  + 2;                           // NSTATE*ED
  float* emb_t  = A_t    + (size_t)NSTATE * ED;         // VOCAB*256
  __hip_bfloat16* xz_b   = (__hip_bfloat16*)(emb_t + (size_t)VOCAB * 256); // NBS*NIP
  __hip_bfloat16* hn_b   = xz_b   + (size_t)NBS * NIP;  // NBS*KD
  __hip_bfloat16* xc_b   = hn_b   + (size_t)NBS * KD;   // NBS*KE
  __hip_bfloat16* dbc_b  = xc_b   + (size_t)NBS * KE;   // NBS*KDT
  __hip_bfloat16* dlt_b  = dbc_b  + (size_t)NBS * KDT;  // NBS*NDT
  __hip_bfloat16* ipb    = dlt_b  + (size_t)NBS * NDT;  // NIP*KD
  __hip_bfloat16* xpb    = ipb    + (size_t)NIP * KD;   // NXP*KE
  __hip_bfloat16* dtwb   = xpb    + (size_t)NXP * KE;   // NDT*KDT
  __hip_bfloat16* opb    = dtwb   + (size_t)NDT * KDT;  // NOP*KE
  __hip_bfloat16* lmb    = opb    + (size_t)NOP * KE;   // VOCAB*KD
  size_t need = (size_t)((char*)(lmb + (size_t)VOCAB * KD) - (char*)ws);
  if (ws_size < need) return;

  k_permute<<<cdiv_h(NBS * D_MODEL, 256), 256, 0, stream>>>(x, h);

  for (int l = 0; l < 2; l++){
    const float* ipw = in_proj_w  + (size_t)l * 2 * ED * D_MODEL;
    const float* cw  = conv_w     + (size_t)l * ED * 4;
    const float* cb  = conv_b     + (size_t)l * ED;
    const float* xpw = x_proj_w   + (size_t)l * DBC_R * ED;
    const float* dtw = dt_proj_w  + (size_t)l * ED * DTR;
    const float* dtb = dt_proj_b  + (size_t)l * ED;
    const float* al  = A_log      + (size_t)l * ED * NSTATE;
    const float* dp  = D_param    + (size_t)l * ED;
    const float* opw = out_proj_w + (size_t)l * D_MODEL * ED;
    const float* nw  = norm_w     + (size_t)l * D_MODEL;

    // per-layer prep: all weight casts + A_t + dbc zero (+ layer0: lm/emb/sumw/stats/logits)
    k_prep<<<cdiv_h(l == 0 ? PREP_N0 : PREP_N1, 256), 256, 0, stream>>>(
        ipw, xpw, dtw, opw, al, lm_head_w, emb_w,
        ipb, xpb, dtwb, opb, A_t, dbc, lmb, logits, emb_t, sumw, stats, l == 0 ? 1 : 0);

    k_rmsnorm_bf16<<<NBS, 256, 0, stream>>>(h, nw, hn_b, D_MODEL, KD);

    // in_proj: xz_b[1536,6272](bf16) = hn_b @ ipb^T
    k_gemm2<1, false, true><<<dim3(NIP / 128, NBS / 128, 1), 256, 0, stream>>>(
        hn_b, ipb, xz_b, KD, NIP, NIP);

    k_conv_silu<<<cdiv_h(B_SZ * KE, 256), 256, 0, stream>>>(xz_b, cw, cb, xc_f, xc_b);

    // x_proj (split-K 8, atomic): dbc[1536,256] += xc_b @ xpb^T
    k_gemm2<8, true, false><<<dim3(NXP / 128, NBS / 128, 8), 256, 0, stream>>>(
        xc_b, xpb, dbc, KE, DBC_LD, DBC_LD);

    // dt_proj: dlt_b[1536,3200](bf16) = dbc_b[1536,128] @ dtwb^T
    k_cast_dbc<<<cdiv_h(NBS * KDT, 256), 256, 0, stream>>>(dbc, dbc_b);
    k_gemm2<1, false, true><<<dim3(NDT / 128, NBS / 128, 1), 256, 0, stream>>>(
        dbc_b, dtwb, dlt_b, KDT, NDT, NDT);

    k_scan2<<<dim3(cdiv_h(ED, 256), B_SZ), 256, 0, stream>>>(
        dlt_b, dbc, dtb, A_t, dp, xz_b, xc_f, xc_b);

    // out_proj (split-K 2, atomic, residual in place): h += xc_b @ opb^T
    k_gemm2<2, true, false><<<dim3(NOP / 128, NBS / 128, 2), 256, 0, stream>>>(
        xc_b, opb, h, KE, D_MODEL, D_MODEL);
  }

  // final norm + lm head (split-K 4, atomic into zeroed logits)
  k_rmsnorm_bf16<<<NBS, 256, 0, stream>>>(h, normf_w, hn_b, D_MODEL, KD);
  k_gemm2<4, true, false><<<dim3(1, NBS / 128, 4), 256, 0, stream>>>(
      hn_b, lmb, logits, KD, VOCAB, VOCAB);

  k_stats_part<<<192, 256, 0, stream>>>(logits, stats);
  k_projfinal<<<NBS, 256, 0, stream>>>(logits, emb_t, sumw, stats,
                                       bn_w, bn_b, emb_b, (float*)d_out);
}